// Round 8
// baseline (263.792 us; speedup 1.0000x reference)
//
#include <hip/hip_runtime.h>

#define VN 49152
#define DEG 20
#define NB 2
#define MROWS (NB * VN)   // 98304 rows

static constexpr float BN_EPS = 1e-5f;

typedef short bf16x8 __attribute__((ext_vector_type(8)));
typedef float floatx4 __attribute__((ext_vector_type(4)));

__device__ __forceinline__ unsigned short f2bf(float f) {
  unsigned int u = __builtin_bit_cast(unsigned int, f);
  u += 0x7FFFu + ((u >> 16) & 1u);            // RNE
  return (unsigned short)(u >> 16);
}
__device__ __forceinline__ float bf2f(unsigned short h) {
  unsigned int u = ((unsigned int)h) << 16;
  return __builtin_bit_cast(float, u);
}
// packed-bf16 tricks: 1 VALU per element
__device__ __forceinline__ float bflo(unsigned int u) {
  return __builtin_bit_cast(float, u << 16);
}
__device__ __forceinline__ float bfhi(unsigned int u) {
  return __builtin_bit_cast(float, u & 0xFFFF0000u);
}
__device__ __forceinline__ unsigned int packbf(float a, float b) {
  return (unsigned int)f2bf(a) | ((unsigned int)f2bf(b) << 16);
}

// BN stats: producers atomicAdd per-block partials into gsum REPLICA
// blockIdx&7 (8 replicas; round-7: -32 us vs single copy). Consumers sum the
// 8 replicas once per block into an LDS scsh cache.
__device__ __forceinline__ void scsh_from8(const float* __restrict__ g,
    int RS, int c, int S, const float* __restrict__ gamma,
    const float* __restrict__ beta, float& sc, float& sh) {
  float s = 0.f, s2 = 0.f;
  #pragma unroll
  for (int r = 0; r < 8; ++r) { s += g[r * RS + c]; s2 += g[r * RS + S + c]; }
  float mean = s * (1.f / MROWS);
  float var  = s2 * (1.f / MROWS) - mean * mean;
  sc = gamma[c] * rsqrtf(var + BN_EPS);
  sh = beta[c] - mean * sc;
}

// Feature planes (64-ch) are stored SWIZZLED as 4 sub-planes
// [batch][chalf][VN][32]: addr(b,v,ch) = ((b*2 + ch/32)*VN + v)*32 + ch%32.
// spmm blocks pin combo via blockIdx%8 (round-6: un-pinned gathers -> 311 MB
// HBM, 2.5x slower).
//
// Chebyshev algebra: t2 = h1@(W0-W2) + x1@W1 + z@(2*W2) with z = L*x1.
// spmm2 is thus a PURE gather (no t1 read, no bn); weight folding is free in
// gemm2 B-staging.
//
// GEMMs: 128-row tiles (M=64 falsified round 5); LDS-transpose epilogues
// (WRITE_SIZE 41->25 MB ideal, round 3); gemm2 uses T14 async-STAGE split +
// As ping-pong dbuf (loads of term k+1 in flight under term k MFMA).
#define TRS 72

// ======================= GEMM1: t1 = x @ W1 + b1 ===========================
#define LDA1 136
__global__ __launch_bounds__(256) void gemm1(const float* __restrict__ X,
    const float* __restrict__ W, const float* __restrict__ bias,
    unsigned short* __restrict__ Y, float* __restrict__ gsum) {
  __shared__ unsigned short As[128 * LDA1];
  __shared__ unsigned short Bs[64 * LDA1];
  __shared__ float sred[128];
  int t = threadIdx.x;
  int row0 = blockIdx.x * 128;
  if (t < 128) sred[t] = 0.f;
  const float* Xt = X + (size_t)row0 * 128;
  #pragma unroll
  for (int c = 0; c < 16; ++c) {
    int f4i = c * 256 + t;
    int row = f4i >> 5, k = (f4i & 31) * 4;
    float4 v = *(const float4*)(Xt + row * 128 + k);
    *(uint2*)(&As[row * LDA1 + k]) = make_uint2(packbf(v.x, v.y), packbf(v.z, v.w));
  }
  #pragma unroll
  for (int c = 0; c < 32; ++c) {
    int f = c * 256 + t;
    int k = f >> 6, n = f & 63;
    Bs[n * LDA1 + k] = f2bf(W[f]);
  }
  __syncthreads();
  int l = t & 63, wv = t >> 6;
  int lr = l & 15, q = l >> 4;
  int m0 = wv * 32;
  floatx4 acc[2][4];
  #pragma unroll
  for (int mi = 0; mi < 2; ++mi)
    #pragma unroll
    for (int ni = 0; ni < 4; ++ni) acc[mi][ni] = (floatx4)(0.f);
  #pragma unroll
  for (int ks = 0; ks < 128; ks += 32) {
    bf16x8 af[2], bfr[4];
    #pragma unroll
    for (int mi = 0; mi < 2; ++mi)
      af[mi] = *(const bf16x8*)(&As[(m0 + mi * 16 + lr) * LDA1 + ks + q * 8]);
    #pragma unroll
    for (int ni = 0; ni < 4; ++ni)
      bfr[ni] = *(const bf16x8*)(&Bs[(ni * 16 + lr) * LDA1 + ks + q * 8]);
    #pragma unroll
    for (int mi = 0; mi < 2; ++mi)
      #pragma unroll
      for (int ni = 0; ni < 4; ++ni)
        acc[mi][ni] = __builtin_amdgcn_mfma_f32_16x16x32_bf16(af[mi], bfr[ni], acc[mi][ni], 0, 0, 0);
  }
  __syncthreads();          // all As/Bs reads done; reuse As as Tr[128][TRS]
  int b = (row0 >= VN) ? 1 : 0;
  int b2 = b * 2, vb0 = row0 - b * VN;
  #pragma unroll
  for (int ni = 0; ni < 4; ++ni) {
    int col = ni * 16 + lr;
    float bv = bias[col];
    float s = 0.f, s2 = 0.f;
    #pragma unroll
    for (int mi = 0; mi < 2; ++mi)
      #pragma unroll
      for (int r = 0; r < 4; ++r) {
        float y = acc[mi][ni][r] + bv;
        s += y; s2 += y * y;
        As[(m0 + mi * 16 + q * 4 + r) * TRS + col] = f2bf(y);
      }
    atomicAdd(&sred[col], s);
    atomicAdd(&sred[64 + col], s2);
  }
  __syncthreads();
  #pragma unroll
  for (int i = 0; i < 4; ++i) {
    int idx = i * 256 + t;
    int p = idx >> 9, rem = idx & 511;
    int rowIdx = rem >> 2, ch0 = (rem & 3) * 8;
    uint4 d = *(const uint4*)(&As[rowIdx * TRS + p * 32 + ch0]);
    *(uint4*)(Y + ((size_t)(b2 + p) * VN + vb0 + rowIdx) * 32 + ch0) = d;
  }
  if (t < 128) atomicAdd(&gsum[(blockIdx.x & 7) * 128 + t], sred[t]);
}

// ---------------- spmm1: x1 = L relu(bn1(t1))  (BN applied inline) ---------
__global__ __launch_bounds__(256) void spmm1(const unsigned short* __restrict__ T1,
    const int* __restrict__ cols, const float* __restrict__ vals,
    const float* __restrict__ gsum, const float* __restrict__ gamma,
    const float* __restrict__ beta, unsigned short* __restrict__ X1out) {
  __shared__ float scsh_s[64];     // [0..31]=sc, [32..63]=sh for block's 32 ch
  int g = blockIdx.x;
  int combo = (g & 7) >> 1;
  int rg = ((g >> 3) << 1) | (g & 1);
  int t = threadIdx.x;
  int cwin0 = (combo & 1) * 32;
  if (t < 32) {
    float sc, sh;
    scsh_from8(gsum, 128, cwin0 + t, 64, gamma, beta, sc, sh);
    scsh_s[t] = sc; scsh_s[32 + t] = sh;
  }
  __syncthreads();
  int wv = t >> 6, lane = t & 63;
  int v = rg * 64 + wv * 16 + (lane >> 2);
  int ch0 = (lane & 3) * 8;
  float sc[8], sh[8];
  #pragma unroll
  for (int j = 0; j < 8; ++j) { sc[j] = scsh_s[ch0 + j]; sh[j] = scsh_s[32 + ch0 + j]; }
  const unsigned short* __restrict__ plane = T1 + (size_t)combo * VN * 32;
  float a[8];
  {
    float w0 = vals[v];
    uint4 d = *(const uint4*)(plane + (size_t)v * 32 + ch0);
    float e[8] = {bflo(d.x), bfhi(d.x), bflo(d.y), bfhi(d.y),
                  bflo(d.z), bfhi(d.z), bflo(d.w), bfhi(d.w)};
    #pragma unroll
    for (int j = 0; j < 8; ++j) {
      float h = fmaf(e[j], sc[j], sh[j]);
      h = h > 0.f ? h : 0.f;
      a[j] = w0 * h;
    }
  }
  const int*   __restrict__ cp = cols + VN + v * DEG;
  const float* __restrict__ vp = vals + VN + v * DEG;
  #pragma unroll
  for (int j = 0; j < DEG; ++j) {
    int cj = cp[j];
    float wj = vp[j];
    uint4 d = *(const uint4*)(plane + (size_t)cj * 32 + ch0);
    float e[8] = {bflo(d.x), bfhi(d.x), bflo(d.y), bfhi(d.y),
                  bflo(d.z), bfhi(d.z), bflo(d.w), bfhi(d.w)};
    #pragma unroll
    for (int i = 0; i < 8; ++i) {
      float h = fmaf(e[i], sc[i], sh[i]);
      h = h > 0.f ? h : 0.f;
      a[i] = fmaf(h, wj, a[i]);
    }
  }
  uint4 o;
  o.x = packbf(a[0], a[1]); o.y = packbf(a[2], a[3]);
  o.z = packbf(a[4], a[5]); o.w = packbf(a[6], a[7]);
  *(uint4*)(X1out + (size_t)combo * VN * 32 + (size_t)v * 32 + ch0) = o;
}

// ------------- spmmz: z = L x1  (pure gather; bn/h1 folded into weights) ---
__global__ __launch_bounds__(256) void spmmz(const unsigned short* __restrict__ X1,
    const int* __restrict__ cols, const float* __restrict__ vals,
    unsigned short* __restrict__ Zout) {
  int g = blockIdx.x;
  int combo = (g & 7) >> 1;
  int rg = ((g >> 3) << 1) | (g & 1);
  int t = threadIdx.x;
  int wv = t >> 6, lane = t & 63;
  int v = rg * 64 + wv * 16 + (lane >> 2);
  int ch0 = (lane & 3) * 8;
  const size_t pbase = (size_t)combo * VN * 32;
  const size_t myoff = pbase + (size_t)v * 32 + ch0;
  const unsigned short* __restrict__ plane = X1 + pbase;
  float a[8];
  {
    float w0 = vals[v];
    uint4 d = *(const uint4*)(X1 + myoff);
    a[0] = w0 * bflo(d.x); a[1] = w0 * bfhi(d.x);
    a[2] = w0 * bflo(d.y); a[3] = w0 * bfhi(d.y);
    a[4] = w0 * bflo(d.z); a[5] = w0 * bfhi(d.z);
    a[6] = w0 * bflo(d.w); a[7] = w0 * bfhi(d.w);
  }
  const int*   __restrict__ cp = cols + VN + v * DEG;
  const float* __restrict__ vp = vals + VN + v * DEG;
  #pragma unroll
  for (int j = 0; j < DEG; ++j) {
    int cj = cp[j];
    float wj = vp[j];
    uint4 d = *(const uint4*)(plane + (size_t)cj * 32 + ch0);
    a[0] = fmaf(bflo(d.x), wj, a[0]); a[1] = fmaf(bfhi(d.x), wj, a[1]);
    a[2] = fmaf(bflo(d.y), wj, a[2]); a[3] = fmaf(bfhi(d.y), wj, a[3]);
    a[4] = fmaf(bflo(d.z), wj, a[4]); a[5] = fmaf(bfhi(d.z), wj, a[5]);
    a[6] = fmaf(bflo(d.w), wj, a[6]); a[7] = fmaf(bfhi(d.w), wj, a[7]);
  }
  uint4 o;
  o.x = packbf(a[0], a[1]); o.y = packbf(a[2], a[3]);
  o.z = packbf(a[4], a[5]); o.w = packbf(a[6], a[7]);
  *(uint4*)(Zout + myoff) = o;
}

// ===== GEMM2: t2 = h1@(W0-W2) + x1@W1 + z@(2*W2) + b2 ======================
// As ping-pong dbuf + all-3 Bs preload; per term: issue next-term loads ->
// MFMA (hides HBM latency, T14) -> ds_write other buffer -> barrier.
// Y aliases X0 (t2 overwrites t1): safe, block-private rows, post-barrier.
#define LDA2 72
__global__ __launch_bounds__(256) void gemm2(const unsigned short* X0,
    const unsigned short* __restrict__ X1, const unsigned short* __restrict__ Z,
    const float* __restrict__ W, const float* __restrict__ bias,
    const float* __restrict__ gsumIn, const float* __restrict__ gamma,
    const float* __restrict__ beta, unsigned short* Y,
    float* __restrict__ gsumOut) {
  __shared__ unsigned short As[2][128 * LDA2];   // 36,864 B
  __shared__ unsigned short Bs[3][64 * LDA2];    // 27,648 B
  __shared__ float sred[128];
  __shared__ float scsh_s[128];   // [0..63]=sc, [64..127]=sh (bn1)
  int t = threadIdx.x;
  int row0 = blockIdx.x * 128;
  int b = (row0 >= VN) ? 1 : 0;
  int b2 = b * 2;
  int vb0 = row0 - b * VN;
  if (t < 128) sred[t] = 0.f;
  if (t >= 128 && t < 192) {
    int c = t - 128;
    float sc, sh;
    scsh_from8(gsumIn, 128, c, 64, gamma, beta, sc, sh);
    scsh_s[c] = sc; scsh_s[64 + c] = sh;
  }
  // stage all three B tiles with weight folding
  #pragma unroll
  for (int c = 0; c < 16; ++c) {
    int f = c * 256 + t;
    int k = f >> 6, n = f & 63;
    float w0 = W[f], w1 = W[4096 + f], w2 = W[8192 + f];
    Bs[0][n * LDA2 + k] = f2bf(w0 - w2);
    Bs[1][n * LDA2 + k] = f2bf(w1);
    Bs[2][n * LDA2 + k] = f2bf(2.f * w2);
  }
  __syncthreads();            // scsh_s ready for term-0 staging
  int kk = (t & 15) * 4;      // staging: k invariant across c8
  int r0 = t >> 4;
  int l = t & 63, wv = t >> 6;
  int lr = l & 15, q = l >> 4;
  int m0 = wv * 32;
  floatx4 acc[2][4];
  #pragma unroll
  for (int mi = 0; mi < 2; ++mi)
    #pragma unroll
    for (int ni = 0; ni < 4; ++ni) acc[mi][ni] = (floatx4)(0.f);

  // stage As[0] = h1 = relu(bn1(t1))
  {
    float tsc[4], tsh[4];
    #pragma unroll
    for (int j = 0; j < 4; ++j) { tsc[j] = scsh_s[kk + j]; tsh[j] = scsh_s[64 + kk + j]; }
    const unsigned short* src0 =
        X0 + ((size_t)(b2 + (kk >> 5)) * VN + vb0) * 32 + (kk & 31);
    #pragma unroll
    for (int c8 = 0; c8 < 8; ++c8) {
      int row = c8 * 16 + r0;
      uint2 rawv = *(const uint2*)(src0 + (size_t)row * 32);
      float y0 = fmaf(bflo(rawv.x), tsc[0], tsh[0]);
      float y1 = fmaf(bfhi(rawv.x), tsc[1], tsh[1]);
      float y2 = fmaf(bflo(rawv.y), tsc[2], tsh[2]);
      float y3 = fmaf(bfhi(rawv.y), tsc[3], tsh[3]);
      y0 = y0 > 0.f ? y0 : 0.f; y1 = y1 > 0.f ? y1 : 0.f;
      y2 = y2 > 0.f ? y2 : 0.f; y3 = y3 > 0.f ? y3 : 0.f;
      *(uint2*)(&As[0][row * LDA2 + kk]) = make_uint2(packbf(y0, y1), packbf(y2, y3));
    }
  }
  __syncthreads();            // As[0] + Bs ready

#define MFMA_TERM(AS, BIDX)                                                     \
  {                                                                             \
    _Pragma("unroll")                                                           \
    for (int ks = 0; ks < 64; ks += 32) {                                       \
      bf16x8 af[2], bfr[4];                                                     \
      _Pragma("unroll")                                                         \
      for (int mi = 0; mi < 2; ++mi)                                            \
        af[mi] = *(const bf16x8*)(&AS[(m0 + mi * 16 + lr) * LDA2 + ks + q * 8]);\
      _Pragma("unroll")                                                         \
      for (int ni = 0; ni < 4; ++ni)                                            \
        bfr[ni] = *(const bf16x8*)(&Bs[BIDX][(ni * 16 + lr) * LDA2 + ks + q * 8]);\
      _Pragma("unroll")                                                         \
      for (int mi = 0; mi < 2; ++mi)                                            \
        _Pragma("unroll")                                                       \
        for (int ni = 0; ni < 4; ++ni)                                          \
          acc[mi][ni] = __builtin_amdgcn_mfma_f32_16x16x32_bf16(af[mi], bfr[ni],\
                                                          acc[mi][ni], 0, 0, 0);\
    }                                                                           \
  }

  uint2 pf[8];
  // ---- term 0 (h1 @ W0-W2); prefetch x1 into regs under the MFMA ----
  {
    const unsigned short* src1 =
        X1 + ((size_t)(b2 + (kk >> 5)) * VN + vb0) * 32 + (kk & 31);
    #pragma unroll
    for (int c8 = 0; c8 < 8; ++c8)
      pf[c8] = *(const uint2*)(src1 + (size_t)(c8 * 16 + r0) * 32);
    MFMA_TERM(As[0], 0);
    #pragma unroll
    for (int c8 = 0; c8 < 8; ++c8)
      *(uint2*)(&As[1][(c8 * 16 + r0) * LDA2 + kk]) = pf[c8];
  }
  __syncthreads();
  // ---- term 1 (x1 @ W1); prefetch z under the MFMA ----
  {
    const unsigned short* src2 =
        Z + ((size_t)(b2 + (kk >> 5)) * VN + vb0) * 32 + (kk & 31);
    #pragma unroll
    for (int c8 = 0; c8 < 8; ++c8)
      pf[c8] = *(const uint2*)(src2 + (size_t)(c8 * 16 + r0) * 32);
    MFMA_TERM(As[1], 1);
    #pragma unroll
    for (int c8 = 0; c8 < 8; ++c8)
      *(uint2*)(&As[0][(c8 * 16 + r0) * LDA2 + kk]) = pf[c8];
  }
  __syncthreads();
  // ---- term 2 (z @ 2*W2) ----
  MFMA_TERM(As[0], 2);
  __syncthreads();
#undef MFMA_TERM

  // epilogue: transpose through As[0] (reuse) -> coalesced 16B stores
  #pragma unroll
  for (int ni = 0; ni < 4; ++ni) {
    int col = ni * 16 + lr;
    float bv = bias[col];
    float s = 0.f, s2 = 0.f;
    #pragma unroll
    for (int mi = 0; mi < 2; ++mi)
      #pragma unroll
      for (int r = 0; r < 4; ++r) {
        float y = acc[mi][ni][r] + bv;
        s += y; s2 += y * y;
        As[0][(m0 + mi * 16 + q * 4 + r) * TRS + col] = f2bf(y);
      }
    atomicAdd(&sred[col], s);
    atomicAdd(&sred[64 + col], s2);
  }
  __syncthreads();
  #pragma unroll
  for (int i = 0; i < 4; ++i) {
    int idx = i * 256 + t;
    int p = idx >> 9, rem = idx & 511;
    int rowIdx = rem >> 2, ch0 = (rem & 3) * 8;
    uint4 d = *(const uint4*)(&As[0][rowIdx * TRS + p * 32 + ch0]);
    *(uint4*)(Y + ((size_t)(b2 + p) * VN + vb0 + rowIdx) * 32 + ch0) = d;
  }
  if (t < 128) atomicAdd(&gsumOut[(blockIdx.x & 7) * 128 + t], sred[t]);
}

// ====== GEMM3: t3 = relu(bn2(t2)) @ W3 + b3  (two 64-col halves, y-grid) ===
__global__ __launch_bounds__(256) void gemm3(const unsigned short* __restrict__ X,
    const float* __restrict__ W, const float* __restrict__ bias,
    const float* __restrict__ gsumIn, const float* __restrict__ gamma,
    const float* __restrict__ beta, unsigned short* __restrict__ Y,
    float* __restrict__ gsumOut) {
  __shared__ unsigned short As[128 * LDA2];
  __shared__ unsigned short Bs[64 * LDA2];
  __shared__ float sred[128];
  __shared__ float scsh_s[128];   // bn2
  int t = threadIdx.x;
  int row0 = blockIdx.x * 128;
  int n0 = blockIdx.y * 64;
  int b = (row0 >= VN) ? 1 : 0;
  int b2 = b * 2;
  int vb0 = row0 - b * VN;
  if (t < 128) sred[t] = 0.f;
  if (t >= 128 && t < 192) {
    int c = t - 128;
    float sc, sh;
    scsh_from8(gsumIn, 128, c, 64, gamma, beta, sc, sh);
    scsh_s[c] = sc; scsh_s[64 + c] = sh;
  }
  __syncthreads();
  int kk = (t & 15) * 4;
  int r0 = t >> 4;
  float tsc[4], tsh[4];
  #pragma unroll
  for (int j = 0; j < 4; ++j) { tsc[j] = scsh_s[kk + j]; tsh[j] = scsh_s[64 + kk + j]; }
  const unsigned short* srcBase =
      X + ((size_t)(b2 + (kk >> 5)) * VN + vb0) * 32 + (kk & 31);
  #pragma unroll
  for (int c8 = 0; c8 < 8; ++c8) {
    int row = c8 * 16 + r0;
    uint2 rawv = *(const uint2*)(srcBase + (size_t)row * 32);
    float y0 = fmaf(bflo(rawv.x), tsc[0], tsh[0]);
    float y1 = fmaf(bfhi(rawv.x), tsc[1], tsh[1]);
    float y2 = fmaf(bflo(rawv.y), tsc[2], tsh[2]);
    float y3 = fmaf(bfhi(rawv.y), tsc[3], tsh[3]);
    y0 = y0 > 0.f ? y0 : 0.f; y1 = y1 > 0.f ? y1 : 0.f;
    y2 = y2 > 0.f ? y2 : 0.f; y3 = y3 > 0.f ? y3 : 0.f;
    *(uint2*)(&As[row * LDA2 + kk]) = make_uint2(packbf(y0, y1), packbf(y2, y3));
  }
  #pragma unroll
  for (int c = 0; c < 16; ++c) {
    int f = c * 256 + t;
    int k = f >> 6, n = f & 63;
    Bs[n * LDA2 + k] = f2bf(W[k * 128 + n0 + n]);
  }
  __syncthreads();
  int l = t & 63, wv = t >> 6;
  int lr = l & 15, q = l >> 4;
  int m0 = wv * 32;
  floatx4 acc[2][4];
  #pragma unroll
  for (int mi = 0; mi < 2; ++mi)
    #pragma unroll
    for (int ni = 0; ni < 4; ++ni) acc[mi][ni] = (floatx4)(0.f);
  #pragma unroll
  for (int ks = 0; ks < 64; ks += 32) {
    bf16x8 af[2], bfr[4];
    #pragma unroll
    for (int mi = 0; mi < 2; ++mi)
      af[mi] = *(const bf16x8*)(&As[(m0 + mi * 16 + lr) * LDA2 + ks + q * 8]);
    #pragma unroll
    for (int ni = 0; ni < 4; ++ni)
      bfr[ni] = *(const bf16x8*)(&Bs[(ni * 16 + lr) * LDA2 + ks + q * 8]);
    #pragma unroll
    for (int mi = 0; mi < 2; ++mi)
      #pragma unroll
      for (int ni = 0; ni < 4; ++ni)
        acc[mi][ni] = __builtin_amdgcn_mfma_f32_16x16x32_bf16(af[mi], bfr[ni], acc[mi][ni], 0, 0, 0);
  }
  __syncthreads();          // As reads done; reuse As as Tr[128][TRS]
  #pragma unroll
  for (int ni = 0; ni < 4; ++ni) {
    int lc = ni * 16 + lr;
    int col = n0 + lc;
    float bv = bias[col];
    float s = 0.f, s2 = 0.f;
    #pragma unroll
    for (int mi = 0; mi < 2; ++mi)
      #pragma unroll
      for (int r = 0; r < 4; ++r) {
        float y = acc[mi][ni][r] + bv;
        s += y; s2 += y * y;
        As[(m0 + mi * 16 + q * 4 + r) * TRS + lc] = f2bf(y);
      }
    atomicAdd(&sred[lc], s);
    atomicAdd(&sred[64 + lc], s2);
  }
  __syncthreads();
  #pragma unroll
  for (int i = 0; i < 4; ++i) {
    int idx = i * 256 + t;
    int rowIdx = idx >> 3, c0 = (idx & 7) * 8;
    uint4 d = *(const uint4*)(&As[rowIdx * TRS + c0]);
    *(uint4*)(Y + (size_t)(row0 + rowIdx) * 128 + n0 + c0) = d;
  }
  // gsumOut replica: [rep][0..127]=sums, [rep][128..255]=sumsq (128 channels)
  if (t < 128) {
    int lc = t & 63, p = t >> 6;
    atomicAdd(&gsumOut[(blockIdx.x & 7) * 256 + p * 128 + n0 + lc], sred[t]);
  }
}

// ---------------- final BN apply + ReLU, bf16 -> fp32 ----------------------
__global__ __launch_bounds__(256) void bn_apply_final(const unsigned short* __restrict__ T,
    float* __restrict__ Y, const float* __restrict__ gsum,
    const float* __restrict__ gamma, const float* __restrict__ beta) {
  __shared__ float scsh_s[256];   // [0..127]=sc, [128..255]=sh (bn3)
  int t = threadIdx.x;
  if (t < 128) {
    float sc, sh;
    scsh_from8(gsum, 256, t, 128, gamma, beta, sc, sh);
    scsh_s[t] = sc; scsh_s[128 + t] = sh;
  }
  __syncthreads();
  size_t i4 = ((size_t)blockIdx.x * 256 + t) * 4;
  int c0 = (int)(i4 & 127);
  ushort4 tv = *(const ushort4*)(T + i4);
  unsigned short sv[4] = {tv.x, tv.y, tv.z, tv.w};
  float ov[4];
  #pragma unroll
  for (int j = 0; j < 4; ++j) {
    int c = c0 + j;
    float y = fmaf(bf2f(sv[j]), scsh_s[c], scsh_s[128 + c]);
    ov[j] = y > 0.f ? y : 0.f;
  }
  *(float4*)(Y + i4) = make_float4(ov[0], ov[1], ov[2], ov[3]);
}

extern "C" void kernel_launch(void* const* d_in, const int* in_sizes, int n_in,
                              void* d_out, int out_size, void* d_ws, size_t ws_size,
                              hipStream_t stream) {
  const float* x    = (const float*)d_in[0];
  const int*   cols = (const int*)  d_in[2];
  const float* vals = (const float*)d_in[3];
  const float* W1   = (const float*)d_in[4];
  const float* b1   = (const float*)d_in[5];
  const float* g1   = (const float*)d_in[6];
  const float* be1  = (const float*)d_in[7];
  const float* W2   = (const float*)d_in[8];
  const float* b2   = (const float*)d_in[9];
  const float* g2   = (const float*)d_in[10];
  const float* be2  = (const float*)d_in[11];
  const float* W3   = (const float*)d_in[12];
  const float* b3   = (const float*)d_in[13];
  const float* g3   = (const float*)d_in[14];
  const float* be3  = (const float*)d_in[15];
  float* out = (float*)d_out;

  const size_t PL = (size_t)MROWS * 64;          // plane elements
  unsigned short* P0 = (unsigned short*)d_ws;    // t1, then t2
  unsigned short* P1 = P0 + PL;                  // x1
  unsigned short* P2 = P1 + PL;                  // z, then t3 [MROWS,128]
  float* ctrl  = (float*)(P2 + 2 * PL);
  float* gsum1 = ctrl;                           // 8 x 128
  float* gsum2 = ctrl + 1024;                    // 8 x 128
  float* gsum3 = ctrl + 2048;                    // 8 x 256

  // zero stat accumulators (8 replicas each)
  hipMemsetAsync(ctrl, 0, 4096 * sizeof(float), stream);

  dim3 blk(256);
  int rowb = MROWS / 128;                        // 768
  int spmm_blocks = 3072;                        // 64 rows x 4 combos
  int ap128_blocks = (int)(PL * 2 / 4 / 256);    // 12288

  // Layer 1
  gemm1<<<rowb, blk, 0, stream>>>(x, W1, b1, P0, gsum1);

  // Layer 2 (K=3 Chebyshev); h1 inline; z = L*x1 pure gather
  spmm1<<<spmm_blocks, blk, 0, stream>>>(P0, cols, vals, gsum1, g1, be1, P1);
  spmmz<<<spmm_blocks, blk, 0, stream>>>(P1, cols, vals, P2);
  gemm2<<<rowb, blk, 0, stream>>>(P0, P1, P2, W2, b2, gsum1, g1, be1, P0, gsum2);

  // Layer 3; bn2-apply fused into gemm3 A-staging; two 64-col halves
  dim3 g3grid(rowb, 2);
  gemm3<<<g3grid, blk, 0, stream>>>(P0, W3, b3, gsum2, g2, be2, P2, gsum3);
  bn_apply_final<<<ap128_blocks, blk, 0, stream>>>(P2, out, gsum3, g3, be3);
}

// Round 9
// 263.080 us; speedup vs baseline: 1.0027x; 1.0027x over previous
//
#include <hip/hip_runtime.h>

#define VN 49152
#define DEG 20
#define NB 2
#define MROWS (NB * VN)   // 98304 rows

static constexpr float BN_EPS = 1e-5f;

typedef short bf16x8 __attribute__((ext_vector_type(8)));
typedef float floatx4 __attribute__((ext_vector_type(4)));

__device__ __forceinline__ unsigned short f2bf(float f) {
  unsigned int u = __builtin_bit_cast(unsigned int, f);
  u += 0x7FFFu + ((u >> 16) & 1u);            // RNE
  return (unsigned short)(u >> 16);
}
__device__ __forceinline__ float bf2f(unsigned short h) {
  unsigned int u = ((unsigned int)h) << 16;
  return __builtin_bit_cast(float, u);
}
// packed-bf16 tricks: 1 VALU per element
__device__ __forceinline__ float bflo(unsigned int u) {
  return __builtin_bit_cast(float, u << 16);
}
__device__ __forceinline__ float bfhi(unsigned int u) {
  return __builtin_bit_cast(float, u & 0xFFFF0000u);
}
__device__ __forceinline__ unsigned int packbf(float a, float b) {
  return (unsigned int)f2bf(a) | ((unsigned int)f2bf(b) << 16);
}

// BN stats: producers atomicAdd per-block partials into gsum REPLICA
// blockIdx&7 (8 replicas; round-7: -32 us vs single copy). Consumers sum the
// 8 replicas once per block into an LDS scsh cache.
__device__ __forceinline__ void scsh_from8(const float* __restrict__ g,
    int RS, int c, int S, const float* __restrict__ gamma,
    const float* __restrict__ beta, float& sc, float& sh) {
  float s = 0.f, s2 = 0.f;
  #pragma unroll
  for (int r = 0; r < 8; ++r) { s += g[r * RS + c]; s2 += g[r * RS + S + c]; }
  float mean = s * (1.f / MROWS);
  float var  = s2 * (1.f / MROWS) - mean * mean;
  sc = gamma[c] * rsqrtf(var + BN_EPS);
  sh = beta[c] - mean * sc;
}

// Feature planes (64-ch) are stored SWIZZLED as 4 sub-planes
// [batch][chalf][VN][32]: addr(b,v,ch) = ((b*2 + ch/32)*VN + v)*32 + ch%32.
// spmm blocks pin combo via blockIdx%8 (round-6: un-pinned gathers -> 311 MB
// HBM, 2.5x slower).
//
// Chebyshev algebra: t2 = h1@(W0-W2) + x1@W1 + z@(2*W2) with z = L*x1.
// spmmz is a PURE gather; weight folding is free in gemm2 B-staging.
//
// GEMMs: 128-row tiles, single-buffered LDS (round-5 AND round-8: residency
// beats pipelining for these short GEMMs — dbuf at 64 KB LDS was neutral-to-
// worse). LDS-transpose epilogues (WRITE 41->25 MB ideal, round 3).
#define TRS 72

// ======================= GEMM1: t1 = x @ W1 + b1 ===========================
#define LDA1 136
__global__ __launch_bounds__(256) void gemm1(const float* __restrict__ X,
    const float* __restrict__ W, const float* __restrict__ bias,
    unsigned short* __restrict__ Y, float* __restrict__ gsum) {
  __shared__ unsigned short As[128 * LDA1];
  __shared__ unsigned short Bs[64 * LDA1];
  __shared__ float sred[128];
  int t = threadIdx.x;
  int row0 = blockIdx.x * 128;
  if (t < 128) sred[t] = 0.f;
  const float* Xt = X + (size_t)row0 * 128;
  #pragma unroll
  for (int c = 0; c < 16; ++c) {
    int f4i = c * 256 + t;
    int row = f4i >> 5, k = (f4i & 31) * 4;
    float4 v = *(const float4*)(Xt + row * 128 + k);
    *(uint2*)(&As[row * LDA1 + k]) = make_uint2(packbf(v.x, v.y), packbf(v.z, v.w));
  }
  #pragma unroll
  for (int c = 0; c < 32; ++c) {
    int f = c * 256 + t;
    int k = f >> 6, n = f & 63;
    Bs[n * LDA1 + k] = f2bf(W[f]);
  }
  __syncthreads();
  int l = t & 63, wv = t >> 6;
  int lr = l & 15, q = l >> 4;
  int m0 = wv * 32;
  floatx4 acc[2][4];
  #pragma unroll
  for (int mi = 0; mi < 2; ++mi)
    #pragma unroll
    for (int ni = 0; ni < 4; ++ni) acc[mi][ni] = (floatx4)(0.f);
  #pragma unroll
  for (int ks = 0; ks < 128; ks += 32) {
    bf16x8 af[2], bfr[4];
    #pragma unroll
    for (int mi = 0; mi < 2; ++mi)
      af[mi] = *(const bf16x8*)(&As[(m0 + mi * 16 + lr) * LDA1 + ks + q * 8]);
    #pragma unroll
    for (int ni = 0; ni < 4; ++ni)
      bfr[ni] = *(const bf16x8*)(&Bs[(ni * 16 + lr) * LDA1 + ks + q * 8]);
    #pragma unroll
    for (int mi = 0; mi < 2; ++mi)
      #pragma unroll
      for (int ni = 0; ni < 4; ++ni)
        acc[mi][ni] = __builtin_amdgcn_mfma_f32_16x16x32_bf16(af[mi], bfr[ni], acc[mi][ni], 0, 0, 0);
  }
  __syncthreads();          // all As/Bs reads done; reuse As as Tr[128][TRS]
  int b = (row0 >= VN) ? 1 : 0;
  int b2 = b * 2, vb0 = row0 - b * VN;
  #pragma unroll
  for (int ni = 0; ni < 4; ++ni) {
    int col = ni * 16 + lr;
    float bv = bias[col];
    float s = 0.f, s2 = 0.f;
    #pragma unroll
    for (int mi = 0; mi < 2; ++mi)
      #pragma unroll
      for (int r = 0; r < 4; ++r) {
        float y = acc[mi][ni][r] + bv;
        s += y; s2 += y * y;
        As[(m0 + mi * 16 + q * 4 + r) * TRS + col] = f2bf(y);
      }
    atomicAdd(&sred[col], s);
    atomicAdd(&sred[64 + col], s2);
  }
  __syncthreads();
  #pragma unroll
  for (int i = 0; i < 4; ++i) {
    int idx = i * 256 + t;
    int p = idx >> 9, rem = idx & 511;
    int rowIdx = rem >> 2, ch0 = (rem & 3) * 8;
    uint4 d = *(const uint4*)(&As[rowIdx * TRS + p * 32 + ch0]);
    *(uint4*)(Y + ((size_t)(b2 + p) * VN + vb0 + rowIdx) * 32 + ch0) = d;
  }
  if (t < 128) atomicAdd(&gsum[(blockIdx.x & 7) * 128 + t], sred[t]);
}

// ---------------- spmm1: x1 = L relu(bn1(t1))  (BN applied inline) ---------
__global__ __launch_bounds__(256) void spmm1(const unsigned short* __restrict__ T1,
    const int* __restrict__ cols, const float* __restrict__ vals,
    const float* __restrict__ gsum, const float* __restrict__ gamma,
    const float* __restrict__ beta, unsigned short* __restrict__ X1out) {
  __shared__ float scsh_s[64];     // [0..31]=sc, [32..63]=sh for block's 32 ch
  int g = blockIdx.x;
  int combo = (g & 7) >> 1;
  int rg = ((g >> 3) << 1) | (g & 1);
  int t = threadIdx.x;
  int cwin0 = (combo & 1) * 32;
  if (t < 32) {
    float sc, sh;
    scsh_from8(gsum, 128, cwin0 + t, 64, gamma, beta, sc, sh);
    scsh_s[t] = sc; scsh_s[32 + t] = sh;
  }
  __syncthreads();
  int wv = t >> 6, lane = t & 63;
  int v = rg * 64 + wv * 16 + (lane >> 2);
  int ch0 = (lane & 3) * 8;
  float sc[8], sh[8];
  #pragma unroll
  for (int j = 0; j < 8; ++j) { sc[j] = scsh_s[ch0 + j]; sh[j] = scsh_s[32 + ch0 + j]; }
  const unsigned short* __restrict__ plane = T1 + (size_t)combo * VN * 32;
  float a[8];
  {
    float w0 = vals[v];
    uint4 d = *(const uint4*)(plane + (size_t)v * 32 + ch0);
    float e[8] = {bflo(d.x), bfhi(d.x), bflo(d.y), bfhi(d.y),
                  bflo(d.z), bfhi(d.z), bflo(d.w), bfhi(d.w)};
    #pragma unroll
    for (int j = 0; j < 8; ++j) {
      float h = fmaf(e[j], sc[j], sh[j]);
      h = h > 0.f ? h : 0.f;
      a[j] = w0 * h;
    }
  }
  const int*   __restrict__ cp = cols + VN + v * DEG;
  const float* __restrict__ vp = vals + VN + v * DEG;
  #pragma unroll
  for (int j = 0; j < DEG; ++j) {
    int cj = cp[j];
    float wj = vp[j];
    uint4 d = *(const uint4*)(plane + (size_t)cj * 32 + ch0);
    float e[8] = {bflo(d.x), bfhi(d.x), bflo(d.y), bfhi(d.y),
                  bflo(d.z), bfhi(d.z), bflo(d.w), bfhi(d.w)};
    #pragma unroll
    for (int i = 0; i < 8; ++i) {
      float h = fmaf(e[i], sc[i], sh[i]);
      h = h > 0.f ? h : 0.f;
      a[i] = fmaf(h, wj, a[i]);
    }
  }
  uint4 o;
  o.x = packbf(a[0], a[1]); o.y = packbf(a[2], a[3]);
  o.z = packbf(a[4], a[5]); o.w = packbf(a[6], a[7]);
  *(uint4*)(X1out + (size_t)combo * VN * 32 + (size_t)v * 32 + ch0) = o;
}

// ------------- spmmz: z = L x1  (pure gather; bn/h1 folded into weights) ---
__global__ __launch_bounds__(256) void spmmz(const unsigned short* __restrict__ X1,
    const int* __restrict__ cols, const float* __restrict__ vals,
    unsigned short* __restrict__ Zout) {
  int g = blockIdx.x;
  int combo = (g & 7) >> 1;
  int rg = ((g >> 3) << 1) | (g & 1);
  int t = threadIdx.x;
  int wv = t >> 6, lane = t & 63;
  int v = rg * 64 + wv * 16 + (lane >> 2);
  int ch0 = (lane & 3) * 8;
  const size_t pbase = (size_t)combo * VN * 32;
  const size_t myoff = pbase + (size_t)v * 32 + ch0;
  const unsigned short* __restrict__ plane = X1 + pbase;
  float a[8];
  {
    float w0 = vals[v];
    uint4 d = *(const uint4*)(X1 + myoff);
    a[0] = w0 * bflo(d.x); a[1] = w0 * bfhi(d.x);
    a[2] = w0 * bflo(d.y); a[3] = w0 * bfhi(d.y);
    a[4] = w0 * bflo(d.z); a[5] = w0 * bfhi(d.z);
    a[6] = w0 * bflo(d.w); a[7] = w0 * bfhi(d.w);
  }
  const int*   __restrict__ cp = cols + VN + v * DEG;
  const float* __restrict__ vp = vals + VN + v * DEG;
  #pragma unroll
  for (int j = 0; j < DEG; ++j) {
    int cj = cp[j];
    float wj = vp[j];
    uint4 d = *(const uint4*)(plane + (size_t)cj * 32 + ch0);
    a[0] = fmaf(bflo(d.x), wj, a[0]); a[1] = fmaf(bfhi(d.x), wj, a[1]);
    a[2] = fmaf(bflo(d.y), wj, a[2]); a[3] = fmaf(bfhi(d.y), wj, a[3]);
    a[4] = fmaf(bflo(d.z), wj, a[4]); a[5] = fmaf(bfhi(d.z), wj, a[5]);
    a[6] = fmaf(bflo(d.w), wj, a[6]); a[7] = fmaf(bfhi(d.w), wj, a[7]);
  }
  uint4 o;
  o.x = packbf(a[0], a[1]); o.y = packbf(a[2], a[3]);
  o.z = packbf(a[4], a[5]); o.w = packbf(a[6], a[7]);
  *(uint4*)(Zout + myoff) = o;
}

// ===== GEMM2: t2 = h1@(W0-W2) + x1@W1 + z@(2*W2) + b2 ======================
// Single-buffered (round-8 dbuf at 64 KB LDS was neutral-to-worse; 28.6 KB
// keeps 5 blocks/CU). Weight folding happens in per-term Bs staging.
// Y aliases X0 (t2 overwrites t1): safe, block-private rows, post-barrier.
#define LDA2 72
__global__ __launch_bounds__(256) void gemm2(const unsigned short* X0,
    const unsigned short* __restrict__ X1, const unsigned short* __restrict__ Z,
    const float* __restrict__ W, const float* __restrict__ bias,
    const float* __restrict__ gsumIn, const float* __restrict__ gamma,
    const float* __restrict__ beta, unsigned short* Y,
    float* __restrict__ gsumOut) {
  __shared__ unsigned short As[128 * LDA2];
  __shared__ unsigned short Bs[64 * LDA2];
  __shared__ float sred[128];
  __shared__ float scsh_s[128];   // [0..63]=sc, [64..127]=sh (bn1)
  int t = threadIdx.x;
  int row0 = blockIdx.x * 128;
  int b = (row0 >= VN) ? 1 : 0;
  int b2 = b * 2;
  int vb0 = row0 - b * VN;
  if (t < 128) sred[t] = 0.f;
  if (t >= 128 && t < 192) {
    int c = t - 128;
    float sc, sh;
    scsh_from8(gsumIn, 128, c, 64, gamma, beta, sc, sh);
    scsh_s[c] = sc; scsh_s[64 + c] = sh;
  }
  __syncthreads();
  int kk = (t & 15) * 4;    // k invariant across c8 (256 % 16 == 0)
  int r0 = t >> 4;
  float tsc[4], tsh[4];
  #pragma unroll
  for (int j = 0; j < 4; ++j) { tsc[j] = scsh_s[kk + j]; tsh[j] = scsh_s[64 + kk + j]; }
  int l = t & 63, wv = t >> 6;
  int lr = l & 15, q = l >> 4;
  int m0 = wv * 32;
  floatx4 acc[2][4];
  #pragma unroll
  for (int mi = 0; mi < 2; ++mi)
    #pragma unroll
    for (int ni = 0; ni < 4; ++ni) acc[mi][ni] = (floatx4)(0.f);

  #pragma unroll
  for (int term = 0; term < 3; ++term) {
    const unsigned short* Xp = (term == 0) ? X0 : (term == 1) ? X1 : Z;
    const unsigned short* srcBase =
        Xp + ((size_t)(b2 + (kk >> 5)) * VN + vb0) * 32 + (kk & 31);
    #pragma unroll
    for (int c8 = 0; c8 < 8; ++c8) {
      int row = c8 * 16 + r0;
      uint2 rawv = *(const uint2*)(srcBase + (size_t)row * 32);
      if (term == 0) {
        float y0 = fmaf(bflo(rawv.x), tsc[0], tsh[0]);
        float y1 = fmaf(bfhi(rawv.x), tsc[1], tsh[1]);
        float y2 = fmaf(bflo(rawv.y), tsc[2], tsh[2]);
        float y3 = fmaf(bfhi(rawv.y), tsc[3], tsh[3]);
        y0 = y0 > 0.f ? y0 : 0.f; y1 = y1 > 0.f ? y1 : 0.f;
        y2 = y2 > 0.f ? y2 : 0.f; y3 = y3 > 0.f ? y3 : 0.f;
        *(uint2*)(&As[row * LDA2 + kk]) = make_uint2(packbf(y0, y1), packbf(y2, y3));
      } else {
        *(uint2*)(&As[row * LDA2 + kk]) = rawv;
      }
    }
    #pragma unroll
    for (int c = 0; c < 16; ++c) {
      int f = c * 256 + t;
      int k = f >> 6, n = f & 63;
      float wv_;
      if (term == 0)      wv_ = W[f] - W[8192 + f];   // W0 - W2
      else if (term == 1) wv_ = W[4096 + f];          // W1
      else                wv_ = 2.f * W[8192 + f];    // 2*W2
      Bs[n * LDA2 + k] = f2bf(wv_);
    }
    __syncthreads();
    #pragma unroll
    for (int ks = 0; ks < 64; ks += 32) {
      bf16x8 af[2], bfr[4];
      #pragma unroll
      for (int mi = 0; mi < 2; ++mi)
        af[mi] = *(const bf16x8*)(&As[(m0 + mi * 16 + lr) * LDA2 + ks + q * 8]);
      #pragma unroll
      for (int ni = 0; ni < 4; ++ni)
        bfr[ni] = *(const bf16x8*)(&Bs[(ni * 16 + lr) * LDA2 + ks + q * 8]);
      #pragma unroll
      for (int mi = 0; mi < 2; ++mi)
        #pragma unroll
        for (int ni = 0; ni < 4; ++ni)
          acc[mi][ni] = __builtin_amdgcn_mfma_f32_16x16x32_bf16(af[mi], bfr[ni], acc[mi][ni], 0, 0, 0);
    }
    __syncthreads();
  }
  // epilogue: transpose through As (reuse) -> coalesced 16B stores
  #pragma unroll
  for (int ni = 0; ni < 4; ++ni) {
    int col = ni * 16 + lr;
    float bv = bias[col];
    float s = 0.f, s2 = 0.f;
    #pragma unroll
    for (int mi = 0; mi < 2; ++mi)
      #pragma unroll
      for (int r = 0; r < 4; ++r) {
        float y = acc[mi][ni][r] + bv;
        s += y; s2 += y * y;
        As[(m0 + mi * 16 + q * 4 + r) * TRS + col] = f2bf(y);
      }
    atomicAdd(&sred[col], s);
    atomicAdd(&sred[64 + col], s2);
  }
  __syncthreads();
  #pragma unroll
  for (int i = 0; i < 4; ++i) {
    int idx = i * 256 + t;
    int p = idx >> 9, rem = idx & 511;
    int rowIdx = rem >> 2, ch0 = (rem & 3) * 8;
    uint4 d = *(const uint4*)(&As[rowIdx * TRS + p * 32 + ch0]);
    *(uint4*)(Y + ((size_t)(b2 + p) * VN + vb0 + rowIdx) * 32 + ch0) = d;
  }
  if (t < 128) atomicAdd(&gsumOut[(blockIdx.x & 7) * 128 + t], sred[t]);
}

// ====== GEMM3: t3 = relu(bn2(t2)) @ W3 + b3  (two 64-col halves, y-grid) ===
__global__ __launch_bounds__(256) void gemm3(const unsigned short* __restrict__ X,
    const float* __restrict__ W, const float* __restrict__ bias,
    const float* __restrict__ gsumIn, const float* __restrict__ gamma,
    const float* __restrict__ beta, unsigned short* __restrict__ Y,
    float* __restrict__ gsumOut) {
  __shared__ unsigned short As[128 * LDA2];
  __shared__ unsigned short Bs[64 * LDA2];
  __shared__ float sred[128];
  __shared__ float scsh_s[128];   // bn2
  int t = threadIdx.x;
  int row0 = blockIdx.x * 128;
  int n0 = blockIdx.y * 64;
  int b = (row0 >= VN) ? 1 : 0;
  int b2 = b * 2;
  int vb0 = row0 - b * VN;
  if (t < 128) sred[t] = 0.f;
  if (t >= 128 && t < 192) {
    int c = t - 128;
    float sc, sh;
    scsh_from8(gsumIn, 128, c, 64, gamma, beta, sc, sh);
    scsh_s[c] = sc; scsh_s[64 + c] = sh;
  }
  __syncthreads();
  int kk = (t & 15) * 4;
  int r0 = t >> 4;
  float tsc[4], tsh[4];
  #pragma unroll
  for (int j = 0; j < 4; ++j) { tsc[j] = scsh_s[kk + j]; tsh[j] = scsh_s[64 + kk + j]; }
  const unsigned short* srcBase =
      X + ((size_t)(b2 + (kk >> 5)) * VN + vb0) * 32 + (kk & 31);
  #pragma unroll
  for (int c8 = 0; c8 < 8; ++c8) {
    int row = c8 * 16 + r0;
    uint2 rawv = *(const uint2*)(srcBase + (size_t)row * 32);
    float y0 = fmaf(bflo(rawv.x), tsc[0], tsh[0]);
    float y1 = fmaf(bfhi(rawv.x), tsc[1], tsh[1]);
    float y2 = fmaf(bflo(rawv.y), tsc[2], tsh[2]);
    float y3 = fmaf(bfhi(rawv.y), tsc[3], tsh[3]);
    y0 = y0 > 0.f ? y0 : 0.f; y1 = y1 > 0.f ? y1 : 0.f;
    y2 = y2 > 0.f ? y2 : 0.f; y3 = y3 > 0.f ? y3 : 0.f;
    *(uint2*)(&As[row * LDA2 + kk]) = make_uint2(packbf(y0, y1), packbf(y2, y3));
  }
  #pragma unroll
  for (int c = 0; c < 16; ++c) {
    int f = c * 256 + t;
    int k = f >> 6, n = f & 63;
    Bs[n * LDA2 + k] = f2bf(W[k * 128 + n0 + n]);
  }
  __syncthreads();
  int l = t & 63, wv = t >> 6;
  int lr = l & 15, q = l >> 4;
  int m0 = wv * 32;
  floatx4 acc[2][4];
  #pragma unroll
  for (int mi = 0; mi < 2; ++mi)
    #pragma unroll
    for (int ni = 0; ni < 4; ++ni) acc[mi][ni] = (floatx4)(0.f);
  #pragma unroll
  for (int ks = 0; ks < 64; ks += 32) {
    bf16x8 af[2], bfr[4];
    #pragma unroll
    for (int mi = 0; mi < 2; ++mi)
      af[mi] = *(const bf16x8*)(&As[(m0 + mi * 16 + lr) * LDA2 + ks + q * 8]);
    #pragma unroll
    for (int ni = 0; ni < 4; ++ni)
      bfr[ni] = *(const bf16x8*)(&Bs[(ni * 16 + lr) * LDA2 + ks + q * 8]);
    #pragma unroll
    for (int mi = 0; mi < 2; ++mi)
      #pragma unroll
      for (int ni = 0; ni < 4; ++ni)
        acc[mi][ni] = __builtin_amdgcn_mfma_f32_16x16x32_bf16(af[mi], bfr[ni], acc[mi][ni], 0, 0, 0);
  }
  __syncthreads();          // As reads done; reuse As as Tr[128][TRS]
  #pragma unroll
  for (int ni = 0; ni < 4; ++ni) {
    int lc = ni * 16 + lr;
    int col = n0 + lc;
    float bv = bias[col];
    float s = 0.f, s2 = 0.f;
    #pragma unroll
    for (int mi = 0; mi < 2; ++mi)
      #pragma unroll
      for (int r = 0; r < 4; ++r) {
        float y = acc[mi][ni][r] + bv;
        s += y; s2 += y * y;
        As[(m0 + mi * 16 + q * 4 + r) * TRS + lc] = f2bf(y);
      }
    atomicAdd(&sred[lc], s);
    atomicAdd(&sred[64 + lc], s2);
  }
  __syncthreads();
  #pragma unroll
  for (int i = 0; i < 4; ++i) {
    int idx = i * 256 + t;
    int rowIdx = idx >> 3, c0 = (idx & 7) * 8;
    uint4 d = *(const uint4*)(&As[rowIdx * TRS + c0]);
    *(uint4*)(Y + (size_t)(row0 + rowIdx) * 128 + n0 + c0) = d;
  }
  // gsumOut replica: [rep][0..127]=sums, [rep][128..255]=sumsq (128 channels)
  if (t < 128) {
    int lc = t & 63, p = t >> 6;
    atomicAdd(&gsumOut[(blockIdx.x & 7) * 256 + p * 128 + n0 + lc], sred[t]);
  }
}

// ---------------- final BN apply + ReLU, bf16 -> fp32 ----------------------
__global__ __launch_bounds__(256) void bn_apply_final(const unsigned short* __restrict__ T,
    float* __restrict__ Y, const float* __restrict__ gsum,
    const float* __restrict__ gamma, const float* __restrict__ beta) {
  __shared__ float scsh_s[256];   // [0..127]=sc, [128..255]=sh (bn3)
  int t = threadIdx.x;
  if (t < 128) {
    float sc, sh;
    scsh_from8(gsum, 256, t, 128, gamma, beta, sc, sh);
    scsh_s[t] = sc; scsh_s[128 + t] = sh;
  }
  __syncthreads();
  size_t i4 = ((size_t)blockIdx.x * 256 + t) * 4;
  int c0 = (int)(i4 & 127);
  ushort4 tv = *(const ushort4*)(T + i4);
  unsigned short sv[4] = {tv.x, tv.y, tv.z, tv.w};
  float ov[4];
  #pragma unroll
  for (int j = 0; j < 4; ++j) {
    int c = c0 + j;
    float y = fmaf(bf2f(sv[j]), scsh_s[c], scsh_s[128 + c]);
    ov[j] = y > 0.f ? y : 0.f;
  }
  *(float4*)(Y + i4) = make_float4(ov[0], ov[1], ov[2], ov[3]);
}

extern "C" void kernel_launch(void* const* d_in, const int* in_sizes, int n_in,
                              void* d_out, int out_size, void* d_ws, size_t ws_size,
                              hipStream_t stream) {
  const float* x    = (const float*)d_in[0];
  const int*   cols = (const int*)  d_in[2];
  const float* vals = (const float*)d_in[3];
  const float* W1   = (const float*)d_in[4];
  const float* b1   = (const float*)d_in[5];
  const float* g1   = (const float*)d_in[6];
  const float* be1  = (const float*)d_in[7];
  const float* W2   = (const float*)d_in[8];
  const float* b2   = (const float*)d_in[9];
  const float* g2   = (const float*)d_in[10];
  const float* be2  = (const float*)d_in[11];
  const float* W3   = (const float*)d_in[12];
  const float* b3   = (const float*)d_in[13];
  const float* g3   = (const float*)d_in[14];
  const float* be3  = (const float*)d_in[15];
  float* out = (float*)d_out;

  const size_t PL = (size_t)MROWS * 64;          // plane elements
  unsigned short* P0 = (unsigned short*)d_ws;    // t1, then t2
  unsigned short* P1 = P0 + PL;                  // x1
  unsigned short* P2 = P1 + PL;                  // z, then t3 [MROWS,128]
  float* ctrl  = (float*)(P2 + 2 * PL);
  float* gsum1 = ctrl;                           // 8 x 128
  float* gsum2 = ctrl + 1024;                    // 8 x 128
  float* gsum3 = ctrl + 2048;                    // 8 x 256

  // zero stat accumulators (8 replicas each)
  hipMemsetAsync(ctrl, 0, 4096 * sizeof(float), stream);

  dim3 blk(256);
  int rowb = MROWS / 128;                        // 768
  int spmm_blocks = 3072;                        // 64 rows x 4 combos
  int ap128_blocks = (int)(PL * 2 / 4 / 256);    // 12288

  // Layer 1
  gemm1<<<rowb, blk, 0, stream>>>(x, W1, b1, P0, gsum1);

  // Layer 2 (K=3 Chebyshev); h1 inline; z = L*x1 pure gather
  spmm1<<<spmm_blocks, blk, 0, stream>>>(P0, cols, vals, gsum1, g1, be1, P1);
  spmmz<<<spmm_blocks, blk, 0, stream>>>(P1, cols, vals, P2);
  gemm2<<<rowb, blk, 0, stream>>>(P0, P1, P2, W2, b2, gsum1, g1, be1, P0, gsum2);

  // Layer 3; bn2-apply fused into gemm3 A-staging; two 64-col halves
  dim3 g3grid(rowb, 2);
  gemm3<<<g3grid, blk, 0, stream>>>(P0, W3, b3, gsum2, g2, be2, P2, gsum3);
  bn_apply_final<<<ap128_blocks, blk, 0, stream>>>(P2, out, gsum3, g3, be3);
}

// Round 10
// 262.457 us; speedup vs baseline: 1.0051x; 1.0024x over previous
//
#include <hip/hip_runtime.h>

#define VN 49152
#define DEG 20
#define NB 2
#define MROWS (NB * VN)   // 98304 rows

static constexpr float BN_EPS = 1e-5f;

typedef short bf16x8 __attribute__((ext_vector_type(8)));
typedef float floatx4 __attribute__((ext_vector_type(4)));

__device__ __forceinline__ unsigned short f2bf(float f) {
  unsigned int u = __builtin_bit_cast(unsigned int, f);
  u += 0x7FFFu + ((u >> 16) & 1u);            // RNE
  return (unsigned short)(u >> 16);
}
__device__ __forceinline__ float bf2f(unsigned short h) {
  unsigned int u = ((unsigned int)h) << 16;
  return __builtin_bit_cast(float, u);
}
// packed-bf16 tricks: 1 VALU per element
__device__ __forceinline__ float bflo(unsigned int u) {
  return __builtin_bit_cast(float, u << 16);
}
__device__ __forceinline__ float bfhi(unsigned int u) {
  return __builtin_bit_cast(float, u & 0xFFFF0000u);
}
__device__ __forceinline__ unsigned int packbf(float a, float b) {
  return (unsigned int)f2bf(a) | ((unsigned int)f2bf(b) << 16);
}

// BN stats: producers atomicAdd per-block partials into gsum REPLICA
// blockIdx&7 (8 replicas; round-7: -32 us vs single copy). Consumers sum the
// 8 replicas once per block into an LDS scsh cache.
__device__ __forceinline__ void scsh_from8(const float* __restrict__ g,
    int RS, int c, int S, const float* __restrict__ gamma,
    const float* __restrict__ beta, float& sc, float& sh) {
  float s = 0.f, s2 = 0.f;
  #pragma unroll
  for (int r = 0; r < 8; ++r) { s += g[r * RS + c]; s2 += g[r * RS + S + c]; }
  float mean = s * (1.f / MROWS);
  float var  = s2 * (1.f / MROWS) - mean * mean;
  sc = gamma[c] * rsqrtf(var + BN_EPS);
  sh = beta[c] - mean * sc;
}

// Feature planes (64-ch) are stored SWIZZLED as 4 sub-planes
// [batch][chalf][VN][32]: addr(b,v,ch) = ((b*2 + ch/32)*VN + v)*32 + ch%32.
// spmm blocks pin combo via blockIdx%8 (round-6: un-pinned gathers -> 311 MB
// HBM, 2.5x slower).
//
// Chebyshev algebra: t2 = h1@(W0-W2) + x1@W1 + z@(2*W2) with z = L*x1.
//
// GEMMs: 128-row tiles; LDS-transpose epilogues (round 3). gemm2 terms 1/2
// stage A via __builtin_amdgcn_global_load_lds width=16 (compiler never
// auto-emits; removes VGPR roundtrip). gll writes linearly, so those terms
// use a linear 128x128B As view with PRE-SWIZZLED global source
// (slot = col16 ^ (row&7)) and the matching XOR on ds_read (m173 pattern,
// both-sides-or-neither) to avoid 16-way bank conflicts at stride 128 B.
#define TRS 72

// ======================= GEMM1: t1 = x @ W1 + b1 ===========================
#define LDA1 136
__global__ __launch_bounds__(256) void gemm1(const float* __restrict__ X,
    const float* __restrict__ W, const float* __restrict__ bias,
    unsigned short* __restrict__ Y, float* __restrict__ gsum) {
  __shared__ __align__(16) unsigned short As[128 * LDA1];
  __shared__ __align__(16) unsigned short Bs[64 * LDA1];
  __shared__ float sred[128];
  int t = threadIdx.x;
  int row0 = blockIdx.x * 128;
  if (t < 128) sred[t] = 0.f;
  const float* Xt = X + (size_t)row0 * 128;
  #pragma unroll
  for (int c = 0; c < 16; ++c) {
    int f4i = c * 256 + t;
    int row = f4i >> 5, k = (f4i & 31) * 4;
    float4 v = *(const float4*)(Xt + row * 128 + k);
    *(uint2*)(&As[row * LDA1 + k]) = make_uint2(packbf(v.x, v.y), packbf(v.z, v.w));
  }
  #pragma unroll
  for (int c = 0; c < 32; ++c) {
    int f = c * 256 + t;
    int k = f >> 6, n = f & 63;
    Bs[n * LDA1 + k] = f2bf(W[f]);
  }
  __syncthreads();
  int l = t & 63, wv = t >> 6;
  int lr = l & 15, q = l >> 4;
  int m0 = wv * 32;
  floatx4 acc[2][4];
  #pragma unroll
  for (int mi = 0; mi < 2; ++mi)
    #pragma unroll
    for (int ni = 0; ni < 4; ++ni) acc[mi][ni] = (floatx4)(0.f);
  #pragma unroll
  for (int ks = 0; ks < 128; ks += 32) {
    bf16x8 af[2], bfr[4];
    #pragma unroll
    for (int mi = 0; mi < 2; ++mi)
      af[mi] = *(const bf16x8*)(&As[(m0 + mi * 16 + lr) * LDA1 + ks + q * 8]);
    #pragma unroll
    for (int ni = 0; ni < 4; ++ni)
      bfr[ni] = *(const bf16x8*)(&Bs[(ni * 16 + lr) * LDA1 + ks + q * 8]);
    #pragma unroll
    for (int mi = 0; mi < 2; ++mi)
      #pragma unroll
      for (int ni = 0; ni < 4; ++ni)
        acc[mi][ni] = __builtin_amdgcn_mfma_f32_16x16x32_bf16(af[mi], bfr[ni], acc[mi][ni], 0, 0, 0);
  }
  __syncthreads();          // all As/Bs reads done; reuse As as Tr[128][TRS]
  int b = (row0 >= VN) ? 1 : 0;
  int b2 = b * 2, vb0 = row0 - b * VN;
  #pragma unroll
  for (int ni = 0; ni < 4; ++ni) {
    int col = ni * 16 + lr;
    float bv = bias[col];
    float s = 0.f, s2 = 0.f;
    #pragma unroll
    for (int mi = 0; mi < 2; ++mi)
      #pragma unroll
      for (int r = 0; r < 4; ++r) {
        float y = acc[mi][ni][r] + bv;
        s += y; s2 += y * y;
        As[(m0 + mi * 16 + q * 4 + r) * TRS + col] = f2bf(y);
      }
    atomicAdd(&sred[col], s);
    atomicAdd(&sred[64 + col], s2);
  }
  __syncthreads();
  #pragma unroll
  for (int i = 0; i < 4; ++i) {
    int idx = i * 256 + t;
    int p = idx >> 9, rem = idx & 511;
    int rowIdx = rem >> 2, ch0 = (rem & 3) * 8;
    uint4 d = *(const uint4*)(&As[rowIdx * TRS + p * 32 + ch0]);
    *(uint4*)(Y + ((size_t)(b2 + p) * VN + vb0 + rowIdx) * 32 + ch0) = d;
  }
  if (t < 128) atomicAdd(&gsum[(blockIdx.x & 7) * 128 + t], sred[t]);
}

// ---------------- spmm1: x1 = L relu(bn1(t1))  (BN applied inline) ---------
__global__ __launch_bounds__(256) void spmm1(const unsigned short* __restrict__ T1,
    const int* __restrict__ cols, const float* __restrict__ vals,
    const float* __restrict__ gsum, const float* __restrict__ gamma,
    const float* __restrict__ beta, unsigned short* __restrict__ X1out) {
  __shared__ float scsh_s[64];     // [0..31]=sc, [32..63]=sh for block's 32 ch
  int g = blockIdx.x;
  int combo = (g & 7) >> 1;
  int rg = ((g >> 3) << 1) | (g & 1);
  int t = threadIdx.x;
  int cwin0 = (combo & 1) * 32;
  if (t < 32) {
    float sc, sh;
    scsh_from8(gsum, 128, cwin0 + t, 64, gamma, beta, sc, sh);
    scsh_s[t] = sc; scsh_s[32 + t] = sh;
  }
  __syncthreads();
  int wv = t >> 6, lane = t & 63;
  int v = rg * 64 + wv * 16 + (lane >> 2);
  int ch0 = (lane & 3) * 8;
  float sc[8], sh[8];
  #pragma unroll
  for (int j = 0; j < 8; ++j) { sc[j] = scsh_s[ch0 + j]; sh[j] = scsh_s[32 + ch0 + j]; }
  const unsigned short* __restrict__ plane = T1 + (size_t)combo * VN * 32;
  float a[8];
  {
    float w0 = vals[v];
    uint4 d = *(const uint4*)(plane + (size_t)v * 32 + ch0);
    float e[8] = {bflo(d.x), bfhi(d.x), bflo(d.y), bfhi(d.y),
                  bflo(d.z), bfhi(d.z), bflo(d.w), bfhi(d.w)};
    #pragma unroll
    for (int j = 0; j < 8; ++j) {
      float h = fmaf(e[j], sc[j], sh[j]);
      h = h > 0.f ? h : 0.f;
      a[j] = w0 * h;
    }
  }
  const int*   __restrict__ cp = cols + VN + v * DEG;
  const float* __restrict__ vp = vals + VN + v * DEG;
  #pragma unroll
  for (int j = 0; j < DEG; ++j) {
    int cj = cp[j];
    float wj = vp[j];
    uint4 d = *(const uint4*)(plane + (size_t)cj * 32 + ch0);
    float e[8] = {bflo(d.x), bfhi(d.x), bflo(d.y), bfhi(d.y),
                  bflo(d.z), bfhi(d.z), bflo(d.w), bfhi(d.w)};
    #pragma unroll
    for (int i = 0; i < 8; ++i) {
      float h = fmaf(e[i], sc[i], sh[i]);
      h = h > 0.f ? h : 0.f;
      a[i] = fmaf(h, wj, a[i]);
    }
  }
  uint4 o;
  o.x = packbf(a[0], a[1]); o.y = packbf(a[2], a[3]);
  o.z = packbf(a[4], a[5]); o.w = packbf(a[6], a[7]);
  *(uint4*)(X1out + (size_t)combo * VN * 32 + (size_t)v * 32 + ch0) = o;
}

// ------------- spmmz: z = L x1  (pure gather; bn/h1 folded into weights) ---
__global__ __launch_bounds__(256) void spmmz(const unsigned short* __restrict__ X1,
    const int* __restrict__ cols, const float* __restrict__ vals,
    unsigned short* __restrict__ Zout) {
  int g = blockIdx.x;
  int combo = (g & 7) >> 1;
  int rg = ((g >> 3) << 1) | (g & 1);
  int t = threadIdx.x;
  int wv = t >> 6, lane = t & 63;
  int v = rg * 64 + wv * 16 + (lane >> 2);
  int ch0 = (lane & 3) * 8;
  const size_t pbase = (size_t)combo * VN * 32;
  const size_t myoff = pbase + (size_t)v * 32 + ch0;
  const unsigned short* __restrict__ plane = X1 + pbase;
  float a[8];
  {
    float w0 = vals[v];
    uint4 d = *(const uint4*)(X1 + myoff);
    a[0] = w0 * bflo(d.x); a[1] = w0 * bfhi(d.x);
    a[2] = w0 * bflo(d.y); a[3] = w0 * bfhi(d.y);
    a[4] = w0 * bflo(d.z); a[5] = w0 * bfhi(d.z);
    a[6] = w0 * bflo(d.w); a[7] = w0 * bfhi(d.w);
  }
  const int*   __restrict__ cp = cols + VN + v * DEG;
  const float* __restrict__ vp = vals + VN + v * DEG;
  #pragma unroll
  for (int j = 0; j < DEG; ++j) {
    int cj = cp[j];
    float wj = vp[j];
    uint4 d = *(const uint4*)(plane + (size_t)cj * 32 + ch0);
    a[0] = fmaf(bflo(d.x), wj, a[0]); a[1] = fmaf(bfhi(d.x), wj, a[1]);
    a[2] = fmaf(bflo(d.y), wj, a[2]); a[3] = fmaf(bfhi(d.y), wj, a[3]);
    a[4] = fmaf(bflo(d.z), wj, a[4]); a[5] = fmaf(bfhi(d.z), wj, a[5]);
    a[6] = fmaf(bflo(d.w), wj, a[6]); a[7] = fmaf(bfhi(d.w), wj, a[7]);
  }
  uint4 o;
  o.x = packbf(a[0], a[1]); o.y = packbf(a[2], a[3]);
  o.z = packbf(a[4], a[5]); o.w = packbf(a[6], a[7]);
  *(uint4*)(Zout + myoff) = o;
}

// ===== GEMM2: t2 = h1@(W0-W2) + x1@W1 + z@(2*W2) + b2 ======================
// Term 0: manual bn1 staging (LDA2=72 view). Terms 1/2: global_load_lds
// width=16 into a LINEAR 128x128B view of the same As buffer, with
// pre-swizzled global source (slot16 = col16 ^ (row&7)) + matching XOR on
// the MFMA ds_reads. Y aliases X0: safe, block-private rows, post-barrier.
#define LDA2 72
__global__ __launch_bounds__(256) void gemm2(const unsigned short* X0,
    const unsigned short* __restrict__ X1, const unsigned short* __restrict__ Z,
    const float* __restrict__ W, const float* __restrict__ bias,
    const float* __restrict__ gsumIn, const float* __restrict__ gamma,
    const float* __restrict__ beta, unsigned short* Y,
    float* __restrict__ gsumOut) {
  __shared__ __align__(16) unsigned short As[128 * LDA2];
  __shared__ __align__(16) unsigned short Bs[64 * LDA2];
  __shared__ float sred[128];
  __shared__ float scsh_s[128];   // [0..63]=sc, [64..127]=sh (bn1)
  int t = threadIdx.x;
  int row0 = blockIdx.x * 128;
  int b = (row0 >= VN) ? 1 : 0;
  int b2 = b * 2;
  int vb0 = row0 - b * VN;
  if (t < 128) sred[t] = 0.f;
  if (t >= 128 && t < 192) {
    int c = t - 128;
    float sc, sh;
    scsh_from8(gsumIn, 128, c, 64, gamma, beta, sc, sh);
    scsh_s[c] = sc; scsh_s[64 + c] = sh;
  }
  __syncthreads();
  int kk = (t & 15) * 4;    // term-0 staging: k invariant across c8
  int r0 = t >> 4;
  int l = t & 63, wvid = t >> 6;
  int lr = l & 15, q = l >> 4;
  int m0 = wvid * 32;
  floatx4 acc[2][4];
  #pragma unroll
  for (int mi = 0; mi < 2; ++mi)
    #pragma unroll
    for (int ni = 0; ni < 4; ++ni) acc[mi][ni] = (floatx4)(0.f);

  // ---- term 0: A = h1 = relu(bn1(t1)), LDA2=72 view; B = W0 - W2 ----------
  {
    float tsc[4], tsh[4];
    #pragma unroll
    for (int j = 0; j < 4; ++j) { tsc[j] = scsh_s[kk + j]; tsh[j] = scsh_s[64 + kk + j]; }
    const unsigned short* srcBase =
        X0 + ((size_t)(b2 + (kk >> 5)) * VN + vb0) * 32 + (kk & 31);
    #pragma unroll
    for (int c8 = 0; c8 < 8; ++c8) {
      int row = c8 * 16 + r0;
      uint2 rawv = *(const uint2*)(srcBase + (size_t)row * 32);
      float y0 = fmaf(bflo(rawv.x), tsc[0], tsh[0]);
      float y1 = fmaf(bfhi(rawv.x), tsc[1], tsh[1]);
      float y2 = fmaf(bflo(rawv.y), tsc[2], tsh[2]);
      float y3 = fmaf(bfhi(rawv.y), tsc[3], tsh[3]);
      y0 = y0 > 0.f ? y0 : 0.f; y1 = y1 > 0.f ? y1 : 0.f;
      y2 = y2 > 0.f ? y2 : 0.f; y3 = y3 > 0.f ? y3 : 0.f;
      *(uint2*)(&As[row * LDA2 + kk]) = make_uint2(packbf(y0, y1), packbf(y2, y3));
    }
    #pragma unroll
    for (int c = 0; c < 16; ++c) {
      int f = c * 256 + t;
      int k = f >> 6, n = f & 63;
      Bs[n * LDA2 + k] = f2bf(W[f] - W[8192 + f]);
    }
    __syncthreads();
    #pragma unroll
    for (int ks = 0; ks < 64; ks += 32) {
      bf16x8 af[2], bfr[4];
      #pragma unroll
      for (int mi = 0; mi < 2; ++mi)
        af[mi] = *(const bf16x8*)(&As[(m0 + mi * 16 + lr) * LDA2 + ks + q * 8]);
      #pragma unroll
      for (int ni = 0; ni < 4; ++ni)
        bfr[ni] = *(const bf16x8*)(&Bs[(ni * 16 + lr) * LDA2 + ks + q * 8]);
      #pragma unroll
      for (int mi = 0; mi < 2; ++mi)
        #pragma unroll
        for (int ni = 0; ni < 4; ++ni)
          acc[mi][ni] = __builtin_amdgcn_mfma_f32_16x16x32_bf16(af[mi], bfr[ni], acc[mi][ni], 0, 0, 0);
    }
    __syncthreads();
  }

  // lane decomposition for gll terms (pre-swizzled source):
  int r_rel = l >> 3;              // 0..7 within 8-row chunk
  int slot16 = l & 7;              // 16B slot within 128B row
  int cc = slot16 ^ r_rel;         // swizzle: slot holds global chunk cc
  int chalf = cc >> 2, c16o = cc & 3;

  // ---- terms 1 (x1 @ W1) and 2 (z @ 2*W2): gll staging, linear+swz view ---
  #pragma unroll
  for (int term = 1; term < 3; ++term) {
    const unsigned short* Xp = (term == 1) ? X1 : Z;
    #pragma unroll
    for (int c = 0; c < 4; ++c) {
      int rbase = wvid * 32 + c * 8;                   // wave-uniform
      const unsigned short* src =
          Xp + ((size_t)(b2 + chalf) * VN + vb0 + rbase + r_rel) * 32 + c16o * 8;
      __builtin_amdgcn_global_load_lds(
          (const __attribute__((address_space(1))) void*)src,
          (__attribute__((address_space(3))) void*)(&As[rbase * 64]),
          16, 0, 0);
    }
    #pragma unroll
    for (int c = 0; c < 16; ++c) {
      int f = c * 256 + t;
      int k = f >> 6, n = f & 63;
      float wv_ = (term == 1) ? W[4096 + f] : 2.f * W[8192 + f];
      Bs[n * LDA2 + k] = f2bf(wv_);
    }
    __syncthreads();   // drains vmcnt: gll data visible
    #pragma unroll
    for (int ks = 0; ks < 64; ks += 32) {
      int kidx = (ks >> 3) + q;                        // 16B chunk index
      bf16x8 af[2], bfr[4];
      #pragma unroll
      for (int mi = 0; mi < 2; ++mi) {
        int R = m0 + mi * 16 + lr;
        const char* ap = (const char*)As + R * 128 + ((kidx ^ (R & 7)) << 4);
        af[mi] = *(const bf16x8*)ap;
      }
      #pragma unroll
      for (int ni = 0; ni < 4; ++ni)
        bfr[ni] = *(const bf16x8*)(&Bs[(ni * 16 + lr) * LDA2 + ks + q * 8]);
      #pragma unroll
      for (int mi = 0; mi < 2; ++mi)
        #pragma unroll
        for (int ni = 0; ni < 4; ++ni)
          acc[mi][ni] = __builtin_amdgcn_mfma_f32_16x16x32_bf16(af[mi], bfr[ni], acc[mi][ni], 0, 0, 0);
    }
    __syncthreads();
  }

  // epilogue: transpose through As (reuse, Tr[128][TRS]) -> coalesced stores
  #pragma unroll
  for (int ni = 0; ni < 4; ++ni) {
    int col = ni * 16 + lr;
    float bv = bias[col];
    float s = 0.f, s2 = 0.f;
    #pragma unroll
    for (int mi = 0; mi < 2; ++mi)
      #pragma unroll
      for (int r = 0; r < 4; ++r) {
        float y = acc[mi][ni][r] + bv;
        s += y; s2 += y * y;
        As[(m0 + mi * 16 + q * 4 + r) * TRS + col] = f2bf(y);
      }
    atomicAdd(&sred[col], s);
    atomicAdd(&sred[64 + col], s2);
  }
  __syncthreads();
  #pragma unroll
  for (int i = 0; i < 4; ++i) {
    int idx = i * 256 + t;
    int p = idx >> 9, rem = idx & 511;
    int rowIdx = rem >> 2, ch0 = (rem & 3) * 8;
    uint4 d = *(const uint4*)(&As[rowIdx * TRS + p * 32 + ch0]);
    *(uint4*)(Y + ((size_t)(b2 + p) * VN + vb0 + rowIdx) * 32 + ch0) = d;
  }
  if (t < 128) atomicAdd(&gsumOut[(blockIdx.x & 7) * 128 + t], sred[t]);
}

// ====== GEMM3: t3 = relu(bn2(t2)) @ W3 + b3  (two 64-col halves, y-grid) ===
__global__ __launch_bounds__(256) void gemm3(const unsigned short* __restrict__ X,
    const float* __restrict__ W, const float* __restrict__ bias,
    const float* __restrict__ gsumIn, const float* __restrict__ gamma,
    const float* __restrict__ beta, unsigned short* __restrict__ Y,
    float* __restrict__ gsumOut) {
  __shared__ __align__(16) unsigned short As[128 * LDA2];
  __shared__ __align__(16) unsigned short Bs[64 * LDA2];
  __shared__ float sred[128];
  __shared__ float scsh_s[128];   // bn2
  int t = threadIdx.x;
  int row0 = blockIdx.x * 128;
  int n0 = blockIdx.y * 64;
  int b = (row0 >= VN) ? 1 : 0;
  int b2 = b * 2;
  int vb0 = row0 - b * VN;
  if (t < 128) sred[t] = 0.f;
  if (t >= 128 && t < 192) {
    int c = t - 128;
    float sc, sh;
    scsh_from8(gsumIn, 128, c, 64, gamma, beta, sc, sh);
    scsh_s[c] = sc; scsh_s[64 + c] = sh;
  }
  __syncthreads();
  int kk = (t & 15) * 4;
  int r0 = t >> 4;
  float tsc[4], tsh[4];
  #pragma unroll
  for (int j = 0; j < 4; ++j) { tsc[j] = scsh_s[kk + j]; tsh[j] = scsh_s[64 + kk + j]; }
  const unsigned short* srcBase =
      X + ((size_t)(b2 + (kk >> 5)) * VN + vb0) * 32 + (kk & 31);
  #pragma unroll
  for (int c8 = 0; c8 < 8; ++c8) {
    int row = c8 * 16 + r0;
    uint2 rawv = *(const uint2*)(srcBase + (size_t)row * 32);
    float y0 = fmaf(bflo(rawv.x), tsc[0], tsh[0]);
    float y1 = fmaf(bfhi(rawv.x), tsc[1], tsh[1]);
    float y2 = fmaf(bflo(rawv.y), tsc[2], tsh[2]);
    float y3 = fmaf(bfhi(rawv.y), tsc[3], tsh[3]);
    y0 = y0 > 0.f ? y0 : 0.f; y1 = y1 > 0.f ? y1 : 0.f;
    y2 = y2 > 0.f ? y2 : 0.f; y3 = y3 > 0.f ? y3 : 0.f;
    *(uint2*)(&As[row * LDA2 + kk]) = make_uint2(packbf(y0, y1), packbf(y2, y3));
  }
  #pragma unroll
  for (int c = 0; c < 16; ++c) {
    int f = c * 256 + t;
    int k = f >> 6, n = f & 63;
    Bs[n * LDA2 + k] = f2bf(W[k * 128 + n0 + n]);
  }
  __syncthreads();
  int l = t & 63, wv = t >> 6;
  int lr = l & 15, q = l >> 4;
  int m0 = wv * 32;
  floatx4 acc[2][4];
  #pragma unroll
  for (int mi = 0; mi < 2; ++mi)
    #pragma unroll
    for (int ni = 0; ni < 4; ++ni) acc[mi][ni] = (floatx4)(0.f);
  #pragma unroll
  for (int ks = 0; ks < 64; ks += 32) {
    bf16x8 af[2], bfr[4];
    #pragma unroll
    for (int mi = 0; mi < 2; ++mi)
      af[mi] = *(const bf16x8*)(&As[(m0 + mi * 16 + lr) * LDA2 + ks + q * 8]);
    #pragma unroll
    for (int ni = 0; ni < 4; ++ni)
      bfr[ni] = *(const bf16x8*)(&Bs[(ni * 16 + lr) * LDA2 + ks + q * 8]);
    #pragma unroll
    for (int mi = 0; mi < 2; ++mi)
      #pragma unroll
      for (int ni = 0; ni < 4; ++ni)
        acc[mi][ni] = __builtin_amdgcn_mfma_f32_16x16x32_bf16(af[mi], bfr[ni], acc[mi][ni], 0, 0, 0);
  }
  __syncthreads();          // As reads done; reuse As as Tr[128][TRS]
  #pragma unroll
  for (int ni = 0; ni < 4; ++ni) {
    int lc = ni * 16 + lr;
    int col = n0 + lc;
    float bv = bias[col];
    float s = 0.f, s2 = 0.f;
    #pragma unroll
    for (int mi = 0; mi < 2; ++mi)
      #pragma unroll
      for (int r = 0; r < 4; ++r) {
        float y = acc[mi][ni][r] + bv;
        s += y; s2 += y * y;
        As[(m0 + mi * 16 + q * 4 + r) * TRS + lc] = f2bf(y);
      }
    atomicAdd(&sred[lc], s);
    atomicAdd(&sred[64 + lc], s2);
  }
  __syncthreads();
  #pragma unroll
  for (int i = 0; i < 4; ++i) {
    int idx = i * 256 + t;
    int rowIdx = idx >> 3, c0 = (idx & 7) * 8;
    uint4 d = *(const uint4*)(&As[rowIdx * TRS + c0]);
    *(uint4*)(Y + (size_t)(row0 + rowIdx) * 128 + n0 + c0) = d;
  }
  // gsumOut replica: [rep][0..127]=sums, [rep][128..255]=sumsq (128 channels)
  if (t < 128) {
    int lc = t & 63, p = t >> 6;
    atomicAdd(&gsumOut[(blockIdx.x & 7) * 256 + p * 128 + n0 + lc], sred[t]);
  }
}

// ---------------- final BN apply + ReLU, bf16 -> fp32 (grid-stride) --------
__global__ __launch_bounds__(256) void bn_apply_final(const unsigned short* __restrict__ T,
    float* __restrict__ Y, const float* __restrict__ gsum,
    const float* __restrict__ gamma, const float* __restrict__ beta) {
  __shared__ float scsh_s[256];   // [0..127]=sc, [128..255]=sh (bn3)
  int t = threadIdx.x;
  if (t < 128) {
    float sc, sh;
    scsh_from8(gsum, 256, t, 128, gamma, beta, sc, sh);
    scsh_s[t] = sc; scsh_s[128 + t] = sh;
  }
  __syncthreads();
  #pragma unroll
  for (int it = 0; it < 4; ++it) {
    size_t i4 = (((size_t)it * 3072 + blockIdx.x) * 256 + t) * 4;
    int c0 = (int)(i4 & 127);
    ushort4 tv = *(const ushort4*)(T + i4);
    unsigned short sv[4] = {tv.x, tv.y, tv.z, tv.w};
    float ov[4];
    #pragma unroll
    for (int j = 0; j < 4; ++j) {
      int c = c0 + j;
      float y = fmaf(bf2f(sv[j]), scsh_s[c], scsh_s[128 + c]);
      ov[j] = y > 0.f ? y : 0.f;
    }
    *(float4*)(Y + i4) = make_float4(ov[0], ov[1], ov[2], ov[3]);
  }
}

extern "C" void kernel_launch(void* const* d_in, const int* in_sizes, int n_in,
                              void* d_out, int out_size, void* d_ws, size_t ws_size,
                              hipStream_t stream) {
  const float* x    = (const float*)d_in[0];
  const int*   cols = (const int*)  d_in[2];
  const float* vals = (const float*)d_in[3];
  const float* W1   = (const float*)d_in[4];
  const float* b1   = (const float*)d_in[5];
  const float* g1   = (const float*)d_in[6];
  const float* be1  = (const float*)d_in[7];
  const float* W2   = (const float*)d_in[8];
  const float* b2   = (const float*)d_in[9];
  const float* g2   = (const float*)d_in[10];
  const float* be2  = (const float*)d_in[11];
  const float* W3   = (const float*)d_in[12];
  const float* b3   = (const float*)d_in[13];
  const float* g3   = (const float*)d_in[14];
  const float* be3  = (const float*)d_in[15];
  float* out = (float*)d_out;

  const size_t PL = (size_t)MROWS * 64;          // plane elements
  unsigned short* P0 = (unsigned short*)d_ws;    // t1, then t2
  unsigned short* P1 = P0 + PL;                  // x1
  unsigned short* P2 = P1 + PL;                  // z, then t3 [MROWS,128]
  float* ctrl  = (float*)(P2 + 2 * PL);
  float* gsum1 = ctrl;                           // 8 x 128
  float* gsum2 = ctrl + 1024;                    // 8 x 128
  float* gsum3 = ctrl + 2048;                    // 8 x 256

  // zero stat accumulators (8 replicas each)
  hipMemsetAsync(ctrl, 0, 4096 * sizeof(float), stream);

  dim3 blk(256);
  int rowb = MROWS / 128;                        // 768
  int spmm_blocks = 3072;                        // 64 rows x 4 combos
  int ap_blocks = 3072;                          // grid-stride x4

  // Layer 1
  gemm1<<<rowb, blk, 0, stream>>>(x, W1, b1, P0, gsum1);

  // Layer 2 (K=3 Chebyshev); h1 inline; z = L*x1 pure gather
  spmm1<<<spmm_blocks, blk, 0, stream>>>(P0, cols, vals, gsum1, g1, be1, P1);
  spmmz<<<spmm_blocks, blk, 0, stream>>>(P1, cols, vals, P2);
  gemm2<<<rowb, blk, 0, stream>>>(P0, P1, P2, W2, b2, gsum1, g1, be1, P0, gsum2);

  // Layer 3; bn2-apply fused into gemm3 A-staging; two 64-col halves
  dim3 g3grid(rowb, 2);
  gemm3<<<g3grid, blk, 0, stream>>>(P0, W3, b3, gsum2, g2, be2, P2, gsum3);
  bn_apply_final<<<ap_blocks, blk, 0, stream>>>(P2, out, gsum3, g3, be3);
}

// Round 11
// 249.132 us; speedup vs baseline: 1.0588x; 1.0535x over previous
//
#include <hip/hip_runtime.h>

#define VN 49152
#define DEG 20
#define NB 2
#define MROWS (NB * VN)   // 98304 rows

static constexpr float BN_EPS = 1e-5f;

typedef short bf16x8 __attribute__((ext_vector_type(8)));
typedef float floatx4 __attribute__((ext_vector_type(4)));

__device__ __forceinline__ unsigned short f2bf(float f) {
  unsigned int u = __builtin_bit_cast(unsigned int, f);
  u += 0x7FFFu + ((u >> 16) & 1u);            // RNE
  return (unsigned short)(u >> 16);
}
__device__ __forceinline__ float bf2f(unsigned short h) {
  unsigned int u = ((unsigned int)h) << 16;
  return __builtin_bit_cast(float, u);
}
// packed-bf16 tricks: 1 VALU per element
__device__ __forceinline__ float bflo(unsigned int u) {
  return __builtin_bit_cast(float, u << 16);
}
__device__ __forceinline__ float bfhi(unsigned int u) {
  return __builtin_bit_cast(float, u & 0xFFFF0000u);
}
__device__ __forceinline__ unsigned int packbf(float a, float b) {
  return (unsigned int)f2bf(a) | ((unsigned int)f2bf(b) << 16);
}

// BN stats: producers atomicAdd per-block partials into gsum REPLICA
// blockIdx&7 (8 replicas; round-7: -32 us vs single copy). Consumers sum the
// 8 replicas once per block into an LDS scsh cache.
__device__ __forceinline__ void scsh_from8(const float* __restrict__ g,
    int RS, int c, int S, const float* __restrict__ gamma,
    const float* __restrict__ beta, float& sc, float& sh) {
  float s = 0.f, s2 = 0.f;
  #pragma unroll
  for (int r = 0; r < 8; ++r) { s += g[r * RS + c]; s2 += g[r * RS + S + c]; }
  float mean = s * (1.f / MROWS);
  float var  = s2 * (1.f / MROWS) - mean * mean;
  sc = gamma[c] * rsqrtf(var + BN_EPS);
  sh = beta[c] - mean * sc;
}

// Feature planes (64-ch) are stored SWIZZLED as 4 sub-planes
// [batch][chalf][VN][32]: addr(b,v,ch) = ((b*2 + ch/32)*VN + v)*32 + ch%32.
// spmm blocks pin combo via blockIdx%8 (round-6: un-pinned gathers -> 311 MB
// HBM, 2.5x slower).
//
// Chebyshev algebra: t2 = h1@(W0-W2) + x1@W1 + z@(2*W2) with z = L*x1.
//
// spmm kernels: explicit 8-deep rolling prefetch (dbuf[j&7]) — the FMA-chain
// consumer otherwise limits outstanding gathers to what the compiler hoists,
// leaving waves serialized on ~200cy L2 latency (round-8 PMC: VALUBusy 30%,
// HBM 14%, occ 17% — latency-bound, not BW/VALU-bound).
#define TRS 72
#define PF 8

// ======================= GEMM1: t1 = x @ W1 + b1 ===========================
#define LDA1 136
__global__ __launch_bounds__(256) void gemm1(const float* __restrict__ X,
    const float* __restrict__ W, const float* __restrict__ bias,
    unsigned short* __restrict__ Y, float* __restrict__ gsum) {
  __shared__ __align__(16) unsigned short As[128 * LDA1];
  __shared__ __align__(16) unsigned short Bs[64 * LDA1];
  __shared__ float sred[128];
  int t = threadIdx.x;
  int row0 = blockIdx.x * 128;
  if (t < 128) sred[t] = 0.f;
  const float* Xt = X + (size_t)row0 * 128;
  #pragma unroll
  for (int c = 0; c < 16; ++c) {
    int f4i = c * 256 + t;
    int row = f4i >> 5, k = (f4i & 31) * 4;
    float4 v = *(const float4*)(Xt + row * 128 + k);
    *(uint2*)(&As[row * LDA1 + k]) = make_uint2(packbf(v.x, v.y), packbf(v.z, v.w));
  }
  #pragma unroll
  for (int c = 0; c < 32; ++c) {
    int f = c * 256 + t;
    int k = f >> 6, n = f & 63;
    Bs[n * LDA1 + k] = f2bf(W[f]);
  }
  __syncthreads();
  int l = t & 63, wv = t >> 6;
  int lr = l & 15, q = l >> 4;
  int m0 = wv * 32;
  floatx4 acc[2][4];
  #pragma unroll
  for (int mi = 0; mi < 2; ++mi)
    #pragma unroll
    for (int ni = 0; ni < 4; ++ni) acc[mi][ni] = (floatx4)(0.f);
  #pragma unroll
  for (int ks = 0; ks < 128; ks += 32) {
    bf16x8 af[2], bfr[4];
    #pragma unroll
    for (int mi = 0; mi < 2; ++mi)
      af[mi] = *(const bf16x8*)(&As[(m0 + mi * 16 + lr) * LDA1 + ks + q * 8]);
    #pragma unroll
    for (int ni = 0; ni < 4; ++ni)
      bfr[ni] = *(const bf16x8*)(&Bs[(ni * 16 + lr) * LDA1 + ks + q * 8]);
    #pragma unroll
    for (int mi = 0; mi < 2; ++mi)
      #pragma unroll
      for (int ni = 0; ni < 4; ++ni)
        acc[mi][ni] = __builtin_amdgcn_mfma_f32_16x16x32_bf16(af[mi], bfr[ni], acc[mi][ni], 0, 0, 0);
  }
  __syncthreads();          // all As/Bs reads done; reuse As as Tr[128][TRS]
  int b = (row0 >= VN) ? 1 : 0;
  int b2 = b * 2, vb0 = row0 - b * VN;
  #pragma unroll
  for (int ni = 0; ni < 4; ++ni) {
    int col = ni * 16 + lr;
    float bv = bias[col];
    float s = 0.f, s2 = 0.f;
    #pragma unroll
    for (int mi = 0; mi < 2; ++mi)
      #pragma unroll
      for (int r = 0; r < 4; ++r) {
        float y = acc[mi][ni][r] + bv;
        s += y; s2 += y * y;
        As[(m0 + mi * 16 + q * 4 + r) * TRS + col] = f2bf(y);
      }
    atomicAdd(&sred[col], s);
    atomicAdd(&sred[64 + col], s2);
  }
  __syncthreads();
  #pragma unroll
  for (int i = 0; i < 4; ++i) {
    int idx = i * 256 + t;
    int p = idx >> 9, rem = idx & 511;
    int rowIdx = rem >> 2, ch0 = (rem & 3) * 8;
    uint4 d = *(const uint4*)(&As[rowIdx * TRS + p * 32 + ch0]);
    *(uint4*)(Y + ((size_t)(b2 + p) * VN + vb0 + rowIdx) * 32 + ch0) = d;
  }
  if (t < 128) atomicAdd(&gsum[(blockIdx.x & 7) * 128 + t], sred[t]);
}

// ---------------- spmm1: x1 = L relu(bn1(t1))  (BN inline, prefetch) -------
__global__ __launch_bounds__(256) void spmm1(const unsigned short* __restrict__ T1,
    const int* __restrict__ cols, const float* __restrict__ vals,
    const float* __restrict__ gsum, const float* __restrict__ gamma,
    const float* __restrict__ beta, unsigned short* __restrict__ X1out) {
  __shared__ float scsh_s[64];     // [0..31]=sc, [32..63]=sh for block's 32 ch
  int g = blockIdx.x;
  int combo = (g & 7) >> 1;
  int rg = ((g >> 3) << 1) | (g & 1);
  int t = threadIdx.x;
  int cwin0 = (combo & 1) * 32;
  if (t < 32) {
    float sc, sh;
    scsh_from8(gsum, 128, cwin0 + t, 64, gamma, beta, sc, sh);
    scsh_s[t] = sc; scsh_s[32 + t] = sh;
  }
  __syncthreads();
  int wv = t >> 6, lane = t & 63;
  int v = rg * 64 + wv * 16 + (lane >> 2);
  int ch0 = (lane & 3) * 8;
  float sc[8], sh[8];
  #pragma unroll
  for (int j = 0; j < 8; ++j) { sc[j] = scsh_s[ch0 + j]; sh[j] = scsh_s[32 + ch0 + j]; }
  const unsigned short* __restrict__ plane = T1 + (size_t)combo * VN * 32;
  const int*   __restrict__ cp = cols + VN + v * DEG;
  const float* __restrict__ vp = vals + VN + v * DEG;
  int cj[DEG];
  #pragma unroll
  for (int j = 0; j < DEG; ++j) cj[j] = cp[j];
  uint4 dbuf[PF];
  uint4 dself = *(const uint4*)(plane + (size_t)v * 32 + ch0);
  #pragma unroll
  for (int j = 0; j < PF; ++j)
    dbuf[j] = *(const uint4*)(plane + (size_t)cj[j] * 32 + ch0);
  float a[8];
  {
    float w0 = vals[v];
    float e[8] = {bflo(dself.x), bfhi(dself.x), bflo(dself.y), bfhi(dself.y),
                  bflo(dself.z), bfhi(dself.z), bflo(dself.w), bfhi(dself.w)};
    #pragma unroll
    for (int j = 0; j < 8; ++j) {
      float h = fmaf(e[j], sc[j], sh[j]);
      h = h > 0.f ? h : 0.f;
      a[j] = w0 * h;
    }
  }
  #pragma unroll
  for (int j = 0; j < DEG; ++j) {
    uint4 d = dbuf[j & (PF - 1)];
    if (j + PF < DEG)
      dbuf[j & (PF - 1)] = *(const uint4*)(plane + (size_t)cj[j + PF] * 32 + ch0);
    float wj = vp[j];
    float e[8] = {bflo(d.x), bfhi(d.x), bflo(d.y), bfhi(d.y),
                  bflo(d.z), bfhi(d.z), bflo(d.w), bfhi(d.w)};
    #pragma unroll
    for (int i = 0; i < 8; ++i) {
      float h = fmaf(e[i], sc[i], sh[i]);
      h = h > 0.f ? h : 0.f;
      a[i] = fmaf(h, wj, a[i]);
    }
  }
  uint4 o;
  o.x = packbf(a[0], a[1]); o.y = packbf(a[2], a[3]);
  o.z = packbf(a[4], a[5]); o.w = packbf(a[6], a[7]);
  *(uint4*)(X1out + (size_t)combo * VN * 32 + (size_t)v * 32 + ch0) = o;
}

// ------------- spmmz: z = L x1  (pure gather, prefetch) --------------------
__global__ __launch_bounds__(256) void spmmz(const unsigned short* __restrict__ X1,
    const int* __restrict__ cols, const float* __restrict__ vals,
    unsigned short* __restrict__ Zout) {
  int g = blockIdx.x;
  int combo = (g & 7) >> 1;
  int rg = ((g >> 3) << 1) | (g & 1);
  int t = threadIdx.x;
  int wv = t >> 6, lane = t & 63;
  int v = rg * 64 + wv * 16 + (lane >> 2);
  int ch0 = (lane & 3) * 8;
  const size_t pbase = (size_t)combo * VN * 32;
  const size_t myoff = pbase + (size_t)v * 32 + ch0;
  const unsigned short* __restrict__ plane = X1 + pbase;
  const int*   __restrict__ cp = cols + VN + v * DEG;
  const float* __restrict__ vp = vals + VN + v * DEG;
  int cj[DEG];
  #pragma unroll
  for (int j = 0; j < DEG; ++j) cj[j] = cp[j];
  uint4 dbuf[PF];
  uint4 dself = *(const uint4*)(X1 + myoff);
  #pragma unroll
  for (int j = 0; j < PF; ++j)
    dbuf[j] = *(const uint4*)(plane + (size_t)cj[j] * 32 + ch0);
  float a[8];
  {
    float w0 = vals[v];
    a[0] = w0 * bflo(dself.x); a[1] = w0 * bfhi(dself.x);
    a[2] = w0 * bflo(dself.y); a[3] = w0 * bfhi(dself.y);
    a[4] = w0 * bflo(dself.z); a[5] = w0 * bfhi(dself.z);
    a[6] = w0 * bflo(dself.w); a[7] = w0 * bfhi(dself.w);
  }
  #pragma unroll
  for (int j = 0; j < DEG; ++j) {
    uint4 d = dbuf[j & (PF - 1)];
    if (j + PF < DEG)
      dbuf[j & (PF - 1)] = *(const uint4*)(plane + (size_t)cj[j + PF] * 32 + ch0);
    float wj = vp[j];
    a[0] = fmaf(bflo(d.x), wj, a[0]); a[1] = fmaf(bfhi(d.x), wj, a[1]);
    a[2] = fmaf(bflo(d.y), wj, a[2]); a[3] = fmaf(bfhi(d.y), wj, a[3]);
    a[4] = fmaf(bflo(d.z), wj, a[4]); a[5] = fmaf(bfhi(d.z), wj, a[5]);
    a[6] = fmaf(bflo(d.w), wj, a[6]); a[7] = fmaf(bfhi(d.w), wj, a[7]);
  }
  uint4 o;
  o.x = packbf(a[0], a[1]); o.y = packbf(a[2], a[3]);
  o.z = packbf(a[4], a[5]); o.w = packbf(a[6], a[7]);
  *(uint4*)(Zout + myoff) = o;
}

// ===== GEMM2: t2 = h1@(W0-W2) + x1@W1 + z@(2*W2) + b2 ======================
// Term 0: manual bn1 staging (LDA2=72 view). Terms 1/2: global_load_lds
// width=16 into a LINEAR 128x128B view of the same As buffer, with
// pre-swizzled global source (slot16 = col16 ^ (row&7)) + matching XOR on
// the MFMA ds_reads. Y aliases X0: safe, block-private rows, post-barrier.
#define LDA2 72
__global__ __launch_bounds__(256) void gemm2(const unsigned short* X0,
    const unsigned short* __restrict__ X1, const unsigned short* __restrict__ Z,
    const float* __restrict__ W, const float* __restrict__ bias,
    const float* __restrict__ gsumIn, const float* __restrict__ gamma,
    const float* __restrict__ beta, unsigned short* Y,
    float* __restrict__ gsumOut) {
  __shared__ __align__(16) unsigned short As[128 * LDA2];
  __shared__ __align__(16) unsigned short Bs[64 * LDA2];
  __shared__ float sred[128];
  __shared__ float scsh_s[128];   // [0..63]=sc, [64..127]=sh (bn1)
  int t = threadIdx.x;
  int row0 = blockIdx.x * 128;
  int b = (row0 >= VN) ? 1 : 0;
  int b2 = b * 2;
  int vb0 = row0 - b * VN;
  if (t < 128) sred[t] = 0.f;
  if (t >= 128 && t < 192) {
    int c = t - 128;
    float sc, sh;
    scsh_from8(gsumIn, 128, c, 64, gamma, beta, sc, sh);
    scsh_s[c] = sc; scsh_s[64 + c] = sh;
  }
  __syncthreads();
  int kk = (t & 15) * 4;    // term-0 staging: k invariant across c8
  int r0 = t >> 4;
  int l = t & 63, wvid = t >> 6;
  int lr = l & 15, q = l >> 4;
  int m0 = wvid * 32;
  floatx4 acc[2][4];
  #pragma unroll
  for (int mi = 0; mi < 2; ++mi)
    #pragma unroll
    for (int ni = 0; ni < 4; ++ni) acc[mi][ni] = (floatx4)(0.f);

  // ---- term 0: A = h1 = relu(bn1(t1)), LDA2=72 view; B = W0 - W2 ----------
  {
    float tsc[4], tsh[4];
    #pragma unroll
    for (int j = 0; j < 4; ++j) { tsc[j] = scsh_s[kk + j]; tsh[j] = scsh_s[64 + kk + j]; }
    const unsigned short* srcBase =
        X0 + ((size_t)(b2 + (kk >> 5)) * VN + vb0) * 32 + (kk & 31);
    #pragma unroll
    for (int c8 = 0; c8 < 8; ++c8) {
      int row = c8 * 16 + r0;
      uint2 rawv = *(const uint2*)(srcBase + (size_t)row * 32);
      float y0 = fmaf(bflo(rawv.x), tsc[0], tsh[0]);
      float y1 = fmaf(bfhi(rawv.x), tsc[1], tsh[1]);
      float y2 = fmaf(bflo(rawv.y), tsc[2], tsh[2]);
      float y3 = fmaf(bfhi(rawv.y), tsc[3], tsh[3]);
      y0 = y0 > 0.f ? y0 : 0.f; y1 = y1 > 0.f ? y1 : 0.f;
      y2 = y2 > 0.f ? y2 : 0.f; y3 = y3 > 0.f ? y3 : 0.f;
      *(uint2*)(&As[row * LDA2 + kk]) = make_uint2(packbf(y0, y1), packbf(y2, y3));
    }
    #pragma unroll
    for (int c = 0; c < 16; ++c) {
      int f = c * 256 + t;
      int k = f >> 6, n = f & 63;
      Bs[n * LDA2 + k] = f2bf(W[f] - W[8192 + f]);
    }
    __syncthreads();
    #pragma unroll
    for (int ks = 0; ks < 64; ks += 32) {
      bf16x8 af[2], bfr[4];
      #pragma unroll
      for (int mi = 0; mi < 2; ++mi)
        af[mi] = *(const bf16x8*)(&As[(m0 + mi * 16 + lr) * LDA2 + ks + q * 8]);
      #pragma unroll
      for (int ni = 0; ni < 4; ++ni)
        bfr[ni] = *(const bf16x8*)(&Bs[(ni * 16 + lr) * LDA2 + ks + q * 8]);
      #pragma unroll
      for (int mi = 0; mi < 2; ++mi)
        #pragma unroll
        for (int ni = 0; ni < 4; ++ni)
          acc[mi][ni] = __builtin_amdgcn_mfma_f32_16x16x32_bf16(af[mi], bfr[ni], acc[mi][ni], 0, 0, 0);
    }
    __syncthreads();
  }

  // lane decomposition for gll terms (pre-swizzled source):
  int r_rel = l >> 3;              // 0..7 within 8-row chunk
  int slot16 = l & 7;              // 16B slot within 128B row
  int cc = slot16 ^ r_rel;         // swizzle: slot holds global chunk cc
  int chalf = cc >> 2, c16o = cc & 3;

  // ---- terms 1 (x1 @ W1) and 2 (z @ 2*W2): gll staging, linear+swz view ---
  #pragma unroll
  for (int term = 1; term < 3; ++term) {
    const unsigned short* Xp = (term == 1) ? X1 : Z;
    #pragma unroll
    for (int c = 0; c < 4; ++c) {
      int rbase = wvid * 32 + c * 8;                   // wave-uniform
      const unsigned short* src =
          Xp + ((size_t)(b2 + chalf) * VN + vb0 + rbase + r_rel) * 32 + c16o * 8;
      __builtin_amdgcn_global_load_lds(
          (const __attribute__((address_space(1))) void*)src,
          (__attribute__((address_space(3))) void*)(&As[rbase * 64]),
          16, 0, 0);
    }
    #pragma unroll
    for (int c = 0; c < 16; ++c) {
      int f = c * 256 + t;
      int k = f >> 6, n = f & 63;
      float wv_ = (term == 1) ? W[4096 + f] : 2.f * W[8192 + f];
      Bs[n * LDA2 + k] = f2bf(wv_);
    }
    __syncthreads();   // drains vmcnt: gll data visible
    #pragma unroll
    for (int ks = 0; ks < 64; ks += 32) {
      int kidx = (ks >> 3) + q;                        // 16B chunk index
      bf16x8 af[2], bfr[4];
      #pragma unroll
      for (int mi = 0; mi < 2; ++mi) {
        int R = m0 + mi * 16 + lr;
        const char* ap = (const char*)As + R * 128 + ((kidx ^ (R & 7)) << 4);
        af[mi] = *(const bf16x8*)ap;
      }
      #pragma unroll
      for (int ni = 0; ni < 4; ++ni)
        bfr[ni] = *(const bf16x8*)(&Bs[(ni * 16 + lr) * LDA2 + ks + q * 8]);
      #pragma unroll
      for (int mi = 0; mi < 2; ++mi)
        #pragma unroll
        for (int ni = 0; ni < 4; ++ni)
          acc[mi][ni] = __builtin_amdgcn_mfma_f32_16x16x32_bf16(af[mi], bfr[ni], acc[mi][ni], 0, 0, 0);
    }
    __syncthreads();
  }

  // epilogue: transpose through As (reuse, Tr[128][TRS]) -> coalesced stores
  #pragma unroll
  for (int ni = 0; ni < 4; ++ni) {
    int col = ni * 16 + lr;
    float bv = bias[col];
    float s = 0.f, s2 = 0.f;
    #pragma unroll
    for (int mi = 0; mi < 2; ++mi)
      #pragma unroll
      for (int r = 0; r < 4; ++r) {
        float y = acc[mi][ni][r] + bv;
        s += y; s2 += y * y;
        As[(m0 + mi * 16 + q * 4 + r) * TRS + col] = f2bf(y);
      }
    atomicAdd(&sred[col], s);
    atomicAdd(&sred[64 + col], s2);
  }
  __syncthreads();
  #pragma unroll
  for (int i = 0; i < 4; ++i) {
    int idx = i * 256 + t;
    int p = idx >> 9, rem = idx & 511;
    int rowIdx = rem >> 2, ch0 = (rem & 3) * 8;
    uint4 d = *(const uint4*)(&As[rowIdx * TRS + p * 32 + ch0]);
    *(uint4*)(Y + ((size_t)(b2 + p) * VN + vb0 + rowIdx) * 32 + ch0) = d;
  }
  if (t < 128) atomicAdd(&gsumOut[(blockIdx.x & 7) * 128 + t], sred[t]);
}

// ====== GEMM3: t3 = relu(bn2(t2)) @ W3 + b3  (two 64-col halves, y-grid) ===
__global__ __launch_bounds__(256) void gemm3(const unsigned short* __restrict__ X,
    const float* __restrict__ W, const float* __restrict__ bias,
    const float* __restrict__ gsumIn, const float* __restrict__ gamma,
    const float* __restrict__ beta, unsigned short* __restrict__ Y,
    float* __restrict__ gsumOut) {
  __shared__ __align__(16) unsigned short As[128 * LDA2];
  __shared__ __align__(16) unsigned short Bs[64 * LDA2];
  __shared__ float sred[128];
  __shared__ float scsh_s[128];   // bn2
  int t = threadIdx.x;
  int row0 = blockIdx.x * 128;
  int n0 = blockIdx.y * 64;
  int b = (row0 >= VN) ? 1 : 0;
  int b2 = b * 2;
  int vb0 = row0 - b * VN;
  if (t < 128) sred[t] = 0.f;
  if (t >= 128 && t < 192) {
    int c = t - 128;
    float sc, sh;
    scsh_from8(gsumIn, 128, c, 64, gamma, beta, sc, sh);
    scsh_s[c] = sc; scsh_s[64 + c] = sh;
  }
  __syncthreads();
  int kk = (t & 15) * 4;
  int r0 = t >> 4;
  float tsc[4], tsh[4];
  #pragma unroll
  for (int j = 0; j < 4; ++j) { tsc[j] = scsh_s[kk + j]; tsh[j] = scsh_s[64 + kk + j]; }
  const unsigned short* srcBase =
      X + ((size_t)(b2 + (kk >> 5)) * VN + vb0) * 32 + (kk & 31);
  #pragma unroll
  for (int c8 = 0; c8 < 8; ++c8) {
    int row = c8 * 16 + r0;
    uint2 rawv = *(const uint2*)(srcBase + (size_t)row * 32);
    float y0 = fmaf(bflo(rawv.x), tsc[0], tsh[0]);
    float y1 = fmaf(bfhi(rawv.x), tsc[1], tsh[1]);
    float y2 = fmaf(bflo(rawv.y), tsc[2], tsh[2]);
    float y3 = fmaf(bfhi(rawv.y), tsc[3], tsh[3]);
    y0 = y0 > 0.f ? y0 : 0.f; y1 = y1 > 0.f ? y1 : 0.f;
    y2 = y2 > 0.f ? y2 : 0.f; y3 = y3 > 0.f ? y3 : 0.f;
    *(uint2*)(&As[row * LDA2 + kk]) = make_uint2(packbf(y0, y1), packbf(y2, y3));
  }
  #pragma unroll
  for (int c = 0; c < 16; ++c) {
    int f = c * 256 + t;
    int k = f >> 6, n = f & 63;
    Bs[n * LDA2 + k] = f2bf(W[k * 128 + n0 + n]);
  }
  __syncthreads();
  int l = t & 63, wv = t >> 6;
  int lr = l & 15, q = l >> 4;
  int m0 = wv * 32;
  floatx4 acc[2][4];
  #pragma unroll
  for (int mi = 0; mi < 2; ++mi)
    #pragma unroll
    for (int ni = 0; ni < 4; ++ni) acc[mi][ni] = (floatx4)(0.f);
  #pragma unroll
  for (int ks = 0; ks < 64; ks += 32) {
    bf16x8 af[2], bfr[4];
    #pragma unroll
    for (int mi = 0; mi < 2; ++mi)
      af[mi] = *(const bf16x8*)(&As[(m0 + mi * 16 + lr) * LDA2 + ks + q * 8]);
    #pragma unroll
    for (int ni = 0; ni < 4; ++ni)
      bfr[ni] = *(const bf16x8*)(&Bs[(ni * 16 + lr) * LDA2 + ks + q * 8]);
    #pragma unroll
    for (int mi = 0; mi < 2; ++mi)
      #pragma unroll
      for (int ni = 0; ni < 4; ++ni)
        acc[mi][ni] = __builtin_amdgcn_mfma_f32_16x16x32_bf16(af[mi], bfr[ni], acc[mi][ni], 0, 0, 0);
  }
  __syncthreads();          // As reads done; reuse As as Tr[128][TRS]
  #pragma unroll
  for (int ni = 0; ni < 4; ++ni) {
    int lc = ni * 16 + lr;
    int col = n0 + lc;
    float bv = bias[col];
    float s = 0.f, s2 = 0.f;
    #pragma unroll
    for (int mi = 0; mi < 2; ++mi)
      #pragma unroll
      for (int r = 0; r < 4; ++r) {
        float y = acc[mi][ni][r] + bv;
        s += y; s2 += y * y;
        As[(m0 + mi * 16 + q * 4 + r) * TRS + lc] = f2bf(y);
      }
    atomicAdd(&sred[lc], s);
    atomicAdd(&sred[64 + lc], s2);
  }
  __syncthreads();
  #pragma unroll
  for (int i = 0; i < 4; ++i) {
    int idx = i * 256 + t;
    int rowIdx = idx >> 3, c0 = (idx & 7) * 8;
    uint4 d = *(const uint4*)(&As[rowIdx * TRS + c0]);
    *(uint4*)(Y + (size_t)(row0 + rowIdx) * 128 + n0 + c0) = d;
  }
  // gsumOut replica: [rep][0..127]=sums, [rep][128..255]=sumsq (128 channels)
  if (t < 128) {
    int lc = t & 63, p = t >> 6;
    atomicAdd(&gsumOut[(blockIdx.x & 7) * 256 + p * 128 + n0 + lc], sred[t]);
  }
}

// ---------------- final BN apply + ReLU, bf16 -> fp32 (grid-stride) --------
__global__ __launch_bounds__(256) void bn_apply_final(const unsigned short* __restrict__ T,
    float* __restrict__ Y, const float* __restrict__ gsum,
    const float* __restrict__ gamma, const float* __restrict__ beta) {
  __shared__ float scsh_s[256];   // [0..127]=sc, [128..255]=sh (bn3)
  int t = threadIdx.x;
  if (t < 128) {
    float sc, sh;
    scsh_from8(gsum, 256, t, 128, gamma, beta, sc, sh);
    scsh_s[t] = sc; scsh_s[128 + t] = sh;
  }
  __syncthreads();
  #pragma unroll
  for (int it = 0; it < 4; ++it) {
    size_t i4 = (((size_t)it * 3072 + blockIdx.x) * 256 + t) * 4;
    int c0 = (int)(i4 & 127);
    ushort4 tv = *(const ushort4*)(T + i4);
    unsigned short sv[4] = {tv.x, tv.y, tv.z, tv.w};
    float ov[4];
    #pragma unroll
    for (int j = 0; j < 4; ++j) {
      int c = c0 + j;
      float y = fmaf(bf2f(sv[j]), scsh_s[c], scsh_s[128 + c]);
      ov[j] = y > 0.f ? y : 0.f;
    }
    *(float4*)(Y + i4) = make_float4(ov[0], ov[1], ov[2], ov[3]);
  }
}

extern "C" void kernel_launch(void* const* d_in, const int* in_sizes, int n_in,
                              void* d_out, int out_size, void* d_ws, size_t ws_size,
                              hipStream_t stream) {
  const float* x    = (const float*)d_in[0];
  const int*   cols = (const int*)  d_in[2];
  const float* vals = (const float*)d_in[3];
  const float* W1   = (const float*)d_in[4];
  const float* b1   = (const float*)d_in[5];
  const float* g1   = (const float*)d_in[6];
  const float* be1  = (const float*)d_in[7];
  const float* W2   = (const float*)d_in[8];
  const float* b2   = (const float*)d_in[9];
  const float* g2   = (const float*)d_in[10];
  const float* be2  = (const float*)d_in[11];
  const float* W3   = (const float*)d_in[12];
  const float* b3   = (const float*)d_in[13];
  const float* g3   = (const float*)d_in[14];
  const float* be3  = (const float*)d_in[15];
  float* out = (float*)d_out;

  const size_t PL = (size_t)MROWS * 64;          // plane elements
  unsigned short* P0 = (unsigned short*)d_ws;    // t1, then t2
  unsigned short* P1 = P0 + PL;                  // x1
  unsigned short* P2 = P1 + PL;                  // z, then t3 [MROWS,128]
  float* ctrl  = (float*)(P2 + 2 * PL);
  float* gsum1 = ctrl;                           // 8 x 128
  float* gsum2 = ctrl + 1024;                    // 8 x 128
  float* gsum3 = ctrl + 2048;                    // 8 x 256

  // zero stat accumulators (8 replicas each)
  hipMemsetAsync(ctrl, 0, 4096 * sizeof(float), stream);

  dim3 blk(256);
  int rowb = MROWS / 128;                        // 768
  int spmm_blocks = 3072;                        // 64 rows x 4 combos
  int ap_blocks = 3072;                          // grid-stride x4

  // Layer 1
  gemm1<<<rowb, blk, 0, stream>>>(x, W1, b1, P0, gsum1);

  // Layer 2 (K=3 Chebyshev); h1 inline; z = L*x1 pure gather
  spmm1<<<spmm_blocks, blk, 0, stream>>>(P0, cols, vals, gsum1, g1, be1, P1);
  spmmz<<<spmm_blocks, blk, 0, stream>>>(P1, cols, vals, P2);
  gemm2<<<rowb, blk, 0, stream>>>(P0, P1, P2, W2, b2, gsum1, g1, be1, P0, gsum2);

  // Layer 3; bn2-apply fused into gemm3 A-staging; two 64-col halves
  dim3 g3grid(rowb, 2);
  gemm3<<<g3grid, blk, 0, stream>>>(P0, W3, b3, gsum2, g2, be2, P2, gsum3);
  bn_apply_final<<<ap_blocks, blk, 0, stream>>>(P2, out, gsum3, g3, be3);
}